// Round 2
// baseline (423.208 us; speedup 1.0000x reference)
//
#include <hip/hip_runtime.h>
#include <hip/hip_bf16.h>

// ---------------------------------------------------------------------------
// GATsmall: 2x GATConv (8 heads) + GCNConv head. N=50000, E=500000 (+N self
// loops). CSR by dst -> gather-only segment ops. Round 2: head-split fused
// aggregation (softmax + weighted gather in one kernel, per-head working set
// 6.4MB -> L2/L3 resident), 128x64 fp32 GEMM with 8x4 micro-tile.
// ---------------------------------------------------------------------------

// ---------------- CSR build ----------------

__global__ __launch_bounds__(256) void init_deg_kernel(int* __restrict__ deg, int n) {
    int i = blockIdx.x * 256 + threadIdx.x;
    if (i < n) deg[i] = 1;  // self loop
}

__global__ __launch_bounds__(256) void hist_kernel(const int* __restrict__ ei, int E,
                                                   int* __restrict__ deg) {
    int e = blockIdx.x * 256 + threadIdx.x;
    if (e < E) atomicAdd(&deg[ei[E + e]], 1);
}

__global__ __launch_bounds__(256) void scanA_kernel(const int* __restrict__ deg,
                                                    int* __restrict__ off,
                                                    int* __restrict__ bsum, int n) {
    __shared__ int buf[256];
    int t = threadIdx.x;
    int i = blockIdx.x * 256 + t;
    int v = (i < n) ? deg[i] : 0;
    buf[t] = v;
    __syncthreads();
    #pragma unroll
    for (int st = 1; st < 256; st <<= 1) {
        int x = (t >= st) ? buf[t - st] : 0;
        __syncthreads();
        buf[t] += x;
        __syncthreads();
    }
    if (i < n) off[i + 1] = buf[t];
    if (t == 255) bsum[blockIdx.x] = buf[255];
}

__global__ __launch_bounds__(256) void scanB_kernel(int* __restrict__ bsum, int nb) {
    __shared__ int buf[256];
    int t = threadIdx.x;
    int v = (t < nb) ? bsum[t] : 0;
    buf[t] = v;
    __syncthreads();
    #pragma unroll
    for (int st = 1; st < 256; st <<= 1) {
        int x = (t >= st) ? buf[t - st] : 0;
        __syncthreads();
        buf[t] += x;
        __syncthreads();
    }
    if (t < nb) bsum[t] = buf[t] - v;  // exclusive prefix of chunk sums
}

__global__ __launch_bounds__(256) void scanC_kernel(const int* __restrict__ deg,
                                                    int* __restrict__ off,
                                                    const int* __restrict__ bsum,
                                                    int* __restrict__ cur, int n) {
    int i = blockIdx.x * 256 + threadIdx.x;
    if (i < n) {
        int o = off[i + 1] + bsum[blockIdx.x];
        off[i + 1] = o;
        cur[i] = o - deg[i];
    }
    if (i == 0) off[0] = 0;
}

__global__ __launch_bounds__(256) void scatter_kernel(const int* __restrict__ ei, int E, int Etot,
                                                      int* __restrict__ cur,
                                                      int* __restrict__ ssrc) {
    int e = blockIdx.x * 256 + threadIdx.x;
    if (e >= Etot) return;
    int s, d;
    if (e < E) { s = ei[e]; d = ei[E + e]; }
    else       { s = e - E; d = e - E; }
    int pos = atomicAdd(&cur[d], 1);
    ssrc[pos] = s;
}

// ---------------- fp32 tiled GEMM: C[M,NC] = A[M,K] @ B[K,NC] ----------------
// BM=128, BN=64, BK=16, 256 threads, 8x4 per-thread micro-tile.
// As transposed [16][132] (132*4B = 33*16B keeps b128 alignment, spreads banks).

template <int K, int NC>
__global__ __launch_bounds__(256) void gemm_kernel(const float* __restrict__ A,
                                                   const float* __restrict__ B,
                                                   float* __restrict__ C, int M) {
    constexpr int BK = 16;
    __shared__ float As[BK][132];
    __shared__ float Bs[BK][64];
    const int tid = threadIdx.x;
    const int bm = blockIdx.y * 128;
    const int bn = blockIdx.x * 64;
    const int ty = tid >> 4;          // 0..15 -> 8 rows each
    const int tx = tid & 15;          // 0..15 -> 4 cols each
    const int ar = tid >> 2;          // 0..63
    const int ac = (tid & 3) << 2;    // 0,4,8,12
    const int br = tid >> 4;          // 0..15
    const int bc = (tid & 15) << 2;   // 0..60
    float acc[8][4] = {};
    for (int k0 = 0; k0 < K; k0 += BK) {
        #pragma unroll
        for (int p = 0; p < 2; ++p) {
            int r = ar + p * 64;
            int row = bm + r;
            float4 v = make_float4(0.f, 0.f, 0.f, 0.f);
            if (row < M) v = *reinterpret_cast<const float4*>(&A[(size_t)row * K + k0 + ac]);
            As[ac + 0][r] = v.x;
            As[ac + 1][r] = v.y;
            As[ac + 2][r] = v.z;
            As[ac + 3][r] = v.w;
        }
        *reinterpret_cast<float4*>(&Bs[br][bc]) =
            *reinterpret_cast<const float4*>(&B[(size_t)(k0 + br) * NC + bn + bc]);
        __syncthreads();
        #pragma unroll
        for (int k = 0; k < BK; ++k) {
            float4 a0 = *reinterpret_cast<const float4*>(&As[k][ty << 3]);
            float4 a1 = *reinterpret_cast<const float4*>(&As[k][(ty << 3) + 4]);
            float4 b  = *reinterpret_cast<const float4*>(&Bs[k][tx << 2]);
            acc[0][0] += a0.x * b.x; acc[0][1] += a0.x * b.y; acc[0][2] += a0.x * b.z; acc[0][3] += a0.x * b.w;
            acc[1][0] += a0.y * b.x; acc[1][1] += a0.y * b.y; acc[1][2] += a0.y * b.z; acc[1][3] += a0.y * b.w;
            acc[2][0] += a0.z * b.x; acc[2][1] += a0.z * b.y; acc[2][2] += a0.z * b.z; acc[2][3] += a0.z * b.w;
            acc[3][0] += a0.w * b.x; acc[3][1] += a0.w * b.y; acc[3][2] += a0.w * b.z; acc[3][3] += a0.w * b.w;
            acc[4][0] += a1.x * b.x; acc[4][1] += a1.x * b.y; acc[4][2] += a1.x * b.z; acc[4][3] += a1.x * b.w;
            acc[5][0] += a1.y * b.x; acc[5][1] += a1.y * b.y; acc[5][2] += a1.y * b.z; acc[5][3] += a1.y * b.w;
            acc[6][0] += a1.z * b.x; acc[6][1] += a1.z * b.y; acc[6][2] += a1.z * b.z; acc[6][3] += a1.z * b.w;
            acc[7][0] += a1.w * b.x; acc[7][1] += a1.w * b.y; acc[7][2] += a1.w * b.z; acc[7][3] += a1.w * b.w;
        }
        __syncthreads();
    }
    #pragma unroll
    for (int r = 0; r < 8; ++r) {
        int row = bm + (ty << 3) + r;
        if (row < M) {
            float4 o = make_float4(acc[r][0], acc[r][1], acc[r][2], acc[r][3]);
            *reinterpret_cast<float4*>(&C[(size_t)row * NC + bn + (tx << 2)]) = o;
        }
    }
}

// ---------------- attention dot products: a_src/a_dst [N,8] ----------------

template <int D>
__global__ __launch_bounds__(256) void attn_dots_kernel(const float* __restrict__ h,
                                                        const float* __restrict__ att_s,
                                                        const float* __restrict__ att_d,
                                                        float* __restrict__ a_s,
                                                        float* __restrict__ a_d, int n) {
    int gid = blockIdx.x * 256 + threadIdx.x;
    if (gid >= n * 8) return;
    int node = gid >> 3, hh = gid & 7;
    const float* hp = h + (size_t)node * 8 * D + hh * D;
    const float* as = att_s + hh * D;
    const float* ad = att_d + hh * D;
    float s1 = 0.f, s2 = 0.f;
    #pragma unroll
    for (int d = 0; d < D; d += 4) {
        float4 hv = *reinterpret_cast<const float4*>(hp + d);
        float4 av = *reinterpret_cast<const float4*>(as + d);
        float4 dv = *reinterpret_cast<const float4*>(ad + d);
        s1 += hv.x * av.x + hv.y * av.y + hv.z * av.z + hv.w * av.w;
        s2 += hv.x * dv.x + hv.y * dv.y + hv.z * dv.z + hv.w * dv.w;
    }
    a_s[gid] = s1;
    a_d[gid] = s2;
}

// ---------------- fused GAT aggregation (softmax + gather), head-split ------
// blockIdx.y = head. Each lane owns 4 channels of one head for one node and
// loops over ALL edges of that node, accumulating Sum(ev) and Sum(ev*h[src]).
// No segment max needed (logits O(1): weights *0.05), exp-safe, alpha exact:
// Sum(ev*h)/(Sum(ev)+eps) == Sum(ev/(s+eps)*h).
// Head-split => per-head gather table (n * DH*4 B) is L2/L3-resident.

template <int C, int DH>
__global__ __launch_bounds__(256) void gat_agg_kernel(const float* __restrict__ hfeat,
                                                      const float* __restrict__ a_src,
                                                      const float* __restrict__ a_dst,
                                                      const int* __restrict__ off,
                                                      const int* __restrict__ ssrc,
                                                      const float* __restrict__ bias,
                                                      float* __restrict__ outp, int n) {
    constexpr int LPN = DH / 4;  // lanes per node (8 for DH=32, 4 for DH=16)
    const int h = blockIdx.y;
    const int node = blockIdx.x * (256 / LPN) + threadIdx.x / LPN;
    if (node >= n) return;
    const int local = threadIdx.x & (LPN - 1);
    const int c0 = h * DH + local * 4;
    const float adst = a_dst[node * 8 + h];
    const int o0 = off[node], o1 = off[node + 1];
    float ax = 0.f, ay = 0.f, az = 0.f, aw = 0.f, ssum = 0.f;
    for (int i = o0; i < o1; ++i) {
        int s = ssrc[i];
        float e = a_src[s * 8 + h] + adst;
        e = e > 0.f ? e : 0.2f * e;
        float ev = __expf(e);
        float4 hv = *reinterpret_cast<const float4*>(&hfeat[(size_t)s * C + c0]);
        ssum += ev;
        ax += ev * hv.x; ay += ev * hv.y; az += ev * hv.z; aw += ev * hv.w;
    }
    float sinv = 1.f / (ssum + 1e-16f);
    float4 bb = *reinterpret_cast<const float4*>(bias + c0);
    float4 o;
    o.x = fmaxf(ax * sinv + bb.x, 0.f);
    o.y = fmaxf(ay * sinv + bb.y, 0.f);
    o.z = fmaxf(az * sinv + bb.z, 0.f);
    o.w = fmaxf(aw * sinv + bb.w, 0.f);
    *reinterpret_cast<float4*>(&outp[(size_t)node * C + c0]) = o;
}

// ---------------- GCN head ----------------

__global__ __launch_bounds__(256) void dinv_kernel(const int* __restrict__ off,
                                                   float* __restrict__ dinv, int n) {
    int i = blockIdx.x * 256 + threadIdx.x;
    if (i < n) {
        int d = off[i + 1] - off[i];
        dinv[i] = rsqrtf((float)d);
    }
}

__global__ __launch_bounds__(256) void gcn_gemm_kernel(const float* __restrict__ A,
                                                       const float* __restrict__ Wg,
                                                       float* __restrict__ g, int n) {
    __shared__ float W[128 * 8];
    for (int i = threadIdx.x; i < 1024; i += 256) W[i] = Wg[i];
    __syncthreads();
    int gid = blockIdx.x * 256 + threadIdx.x;
    if (gid >= n * 8) return;
    int node = gid >> 3, c = gid & 7;
    const float* ap = A + (size_t)node * 128;
    float acc = 0.f;
    #pragma unroll
    for (int k = 0; k < 128; k += 4) {
        float4 av = *reinterpret_cast<const float4*>(ap + k);
        acc += av.x * W[(k + 0) * 8 + c] + av.y * W[(k + 1) * 8 + c] +
               av.z * W[(k + 2) * 8 + c] + av.w * W[(k + 3) * 8 + c];
    }
    g[gid] = acc;
}

__global__ __launch_bounds__(256) void gcn_agg_kernel(const float* __restrict__ g,
                                                      const float* __restrict__ dinv,
                                                      const int* __restrict__ off,
                                                      const int* __restrict__ ssrc,
                                                      const float* __restrict__ bg,
                                                      float* __restrict__ outp, int n) {
    int gid = blockIdx.x * 256 + threadIdx.x;
    if (gid >= n * 8) return;
    int node = gid >> 3, c = gid & 7;
    int o0 = off[node], o1 = off[node + 1];
    float acc = 0.f;
    for (int i = o0; i < o1; ++i) {
        int s = ssrc[i];
        acc += g[(size_t)s * 8 + c] * dinv[s];
    }
    outp[gid] = acc * dinv[node] + bg[c];
}

// ---------------- launch ----------------

extern "C" void kernel_launch(void* const* d_in, const int* in_sizes, int n_in,
                              void* d_out, int out_size, void* d_ws, size_t ws_size,
                              hipStream_t stream) {
    const float* x      = (const float*)d_in[0];
    const int*   ei     = (const int*)d_in[1];
    const float* W1     = (const float*)d_in[2];
    const float* att_s1 = (const float*)d_in[3];
    const float* att_d1 = (const float*)d_in[4];
    const float* b1     = (const float*)d_in[5];
    const float* W2     = (const float*)d_in[6];
    const float* att_s2 = (const float*)d_in[7];
    const float* att_d2 = (const float*)d_in[8];
    const float* b2     = (const float*)d_in[9];
    const float* Wg     = (const float*)d_in[10];
    const float* bg     = (const float*)d_in[11];
    float* out = (float*)d_out;

    const int n    = in_sizes[0] / 128;  // 50000
    const int E    = in_sizes[1] / 2;    // 500000
    const int Etot = E + n;              // 550000

    float* ws    = (float*)d_ws;
    float* h1    = ws;                           // [n,256]
    float* out1  = h1 + (size_t)n * 256;         // [n,256]
    float* h2    = h1;                           // [n,128] (h1 dead after agg1)
    float* out2  = h1 + (size_t)n * 128;         // [n,128]
    float* a_src = out1 + (size_t)n * 256;       // [n,8]
    float* a_dst = a_src + (size_t)n * 8;        // [n,8]
    float* g     = a_dst + (size_t)n * 8;        // [n,8]
    float* dinv  = g + (size_t)n * 8;            // [n]
    int*   off   = (int*)(dinv + n);             // [n+1]
    int*   deg   = off + (n + 1);                // [n]
    int*   cur   = deg + n;                      // [n]
    int*   ssrc  = cur + n;                      // [Etot]
    int*   bsum  = ssrc + Etot;                  // [<=256]

    const dim3 b256(256);
    const int nch = (n + 255) / 256;

    // CSR build
    init_deg_kernel<<<nch, b256, 0, stream>>>(deg, n);
    hist_kernel<<<(E + 255) / 256, b256, 0, stream>>>(ei, E, deg);
    scanA_kernel<<<nch, b256, 0, stream>>>(deg, off, bsum, n);
    scanB_kernel<<<1, b256, 0, stream>>>(bsum, nch);
    scanC_kernel<<<nch, b256, 0, stream>>>(deg, off, bsum, cur, n);
    scatter_kernel<<<(Etot + 255) / 256, b256, 0, stream>>>(ei, E, Etot, cur, ssrc);

    // layer 1: GAT(128 -> 8x32)
    gemm_kernel<128, 256><<<dim3(4, (n + 127) / 128), b256, 0, stream>>>(x, W1, h1, n);
    attn_dots_kernel<32><<<(n * 8 + 255) / 256, b256, 0, stream>>>(h1, att_s1, att_d1, a_src, a_dst, n);
    gat_agg_kernel<256, 32><<<dim3((n + 31) / 32, 8), b256, 0, stream>>>(h1, a_src, a_dst, off, ssrc, b1, out1, n);

    // layer 2: GAT(256 -> 8x16)
    gemm_kernel<256, 128><<<dim3(2, (n + 127) / 128), b256, 0, stream>>>(out1, W2, h2, n);
    attn_dots_kernel<16><<<(n * 8 + 255) / 256, b256, 0, stream>>>(h2, att_s2, att_d2, a_src, a_dst, n);
    gat_agg_kernel<128, 16><<<dim3((n + 63) / 64, 8), b256, 0, stream>>>(h2, a_src, a_dst, off, ssrc, b2, out2, n);

    // GCN head
    dinv_kernel<<<nch, b256, 0, stream>>>(off, dinv, n);
    gcn_gemm_kernel<<<(n * 8 + 255) / 256, b256, 0, stream>>>(out2, Wg, g, n);
    gcn_agg_kernel<<<(n * 8 + 255) / 256, b256, 0, stream>>>(g, dinv, off, ssrc, bg, out, n);
}

// Round 4
// 403.791 us; speedup vs baseline: 1.0481x; 1.0481x over previous
//
#include <hip/hip_runtime.h>
#include <hip/hip_bf16.h>

// ---------------------------------------------------------------------------
// GATsmall: 2x GATConv (8 heads) + GCNConv head. N=50000, E=500000 (+N self
// loops). CSR by dst -> gather-only segment ops. Round 4 (= R3 resubmit,
// infra failure): fused softmax+gather agg with 64-lane/node layout and
// 4x-unrolled edge loop (latency hiding), 128x128 fp32 GEMM with 8x8
// micro-tile, launch-count trims. hipMemsetAsync -> zero kernel (capture-safe).
// ---------------------------------------------------------------------------

// ---------------- CSR build ----------------

__global__ __launch_bounds__(256) void zero_deg_kernel(int* __restrict__ deg, int n) {
    int i = blockIdx.x * 256 + threadIdx.x;
    if (i < n) deg[i] = 0;
}

__global__ __launch_bounds__(256) void hist_kernel(const int* __restrict__ ei, int E, int Etot,
                                                   int* __restrict__ deg) {
    int e = blockIdx.x * 256 + threadIdx.x;
    if (e >= Etot) return;
    int d = (e < E) ? ei[E + e] : (e - E);  // tail = self loops
    atomicAdd(&deg[d], 1);
}

__global__ __launch_bounds__(256) void scanA_kernel(const int* __restrict__ deg,
                                                    int* __restrict__ off,
                                                    int* __restrict__ bsum, int n) {
    __shared__ int buf[256];
    int t = threadIdx.x;
    int i = blockIdx.x * 256 + t;
    int v = (i < n) ? deg[i] : 0;
    buf[t] = v;
    __syncthreads();
    #pragma unroll
    for (int st = 1; st < 256; st <<= 1) {
        int x = (t >= st) ? buf[t - st] : 0;
        __syncthreads();
        buf[t] += x;
        __syncthreads();
    }
    if (i < n) off[i + 1] = buf[t];
    if (t == 255) bsum[blockIdx.x] = buf[255];
}

__global__ __launch_bounds__(256) void scanB_kernel(int* __restrict__ bsum, int nb) {
    __shared__ int buf[256];
    int t = threadIdx.x;
    int v = (t < nb) ? bsum[t] : 0;
    buf[t] = v;
    __syncthreads();
    #pragma unroll
    for (int st = 1; st < 256; st <<= 1) {
        int x = (t >= st) ? buf[t - st] : 0;
        __syncthreads();
        buf[t] += x;
        __syncthreads();
    }
    if (t < nb) bsum[t] = buf[t] - v;  // exclusive prefix of chunk sums
}

// also computes dinv for the GCN head (deg is final here)
__global__ __launch_bounds__(256) void scanC_kernel(const int* __restrict__ deg,
                                                    int* __restrict__ off,
                                                    const int* __restrict__ bsum,
                                                    int* __restrict__ cur,
                                                    float* __restrict__ dinv, int n) {
    int i = blockIdx.x * 256 + threadIdx.x;
    if (i < n) {
        int o = off[i + 1] + bsum[blockIdx.x];
        off[i + 1] = o;
        cur[i] = o - deg[i];
        dinv[i] = rsqrtf((float)deg[i]);  // deg >= 1 (self loop)
    }
    if (i == 0) off[0] = 0;
}

__global__ __launch_bounds__(256) void scatter_kernel(const int* __restrict__ ei, int E, int Etot,
                                                      int* __restrict__ cur,
                                                      int* __restrict__ ssrc) {
    int e = blockIdx.x * 256 + threadIdx.x;
    if (e >= Etot) return;
    int s, d;
    if (e < E) { s = ei[e]; d = ei[E + e]; }
    else       { s = e - E; d = e - E; }
    int pos = atomicAdd(&cur[d], 1);
    ssrc[pos] = s;
}

// ---------------- fp32 tiled GEMM: C[M,NC] = A[M,K] @ B[K,NC] ----------------
// BM=BN=128, BK=16, 256 threads, 8x8 per-thread micro-tile.
// As transposed [16][132] (33*16B rows: aligned b128, banks spread).

template <int K, int NC>
__global__ __launch_bounds__(256) void gemm_kernel(const float* __restrict__ A,
                                                   const float* __restrict__ B,
                                                   float* __restrict__ C, int M) {
    constexpr int BK = 16;
    __shared__ float As[BK][132];
    __shared__ float Bs[BK][128];
    const int tid = threadIdx.x;
    const int bm = blockIdx.y * 128;
    const int bn = blockIdx.x * 128;
    const int ty = tid >> 4;          // 0..15 -> 8 rows
    const int tx = tid & 15;          // 0..15 -> 8 cols
    const int ar = tid >> 1;          // 0..127
    const int ac = (tid & 1) << 3;    // 0 or 8
    const int br = tid >> 4;          // 0..15
    const int bc = (tid & 15) << 3;   // 0..120
    float acc[8][8] = {};
    for (int k0 = 0; k0 < K; k0 += BK) {
        int row = bm + ar;
        float4 v0 = make_float4(0.f, 0.f, 0.f, 0.f);
        float4 v1 = make_float4(0.f, 0.f, 0.f, 0.f);
        if (row < M) {
            v0 = *reinterpret_cast<const float4*>(&A[(size_t)row * K + k0 + ac]);
            v1 = *reinterpret_cast<const float4*>(&A[(size_t)row * K + k0 + ac + 4]);
        }
        As[ac + 0][ar] = v0.x; As[ac + 1][ar] = v0.y; As[ac + 2][ar] = v0.z; As[ac + 3][ar] = v0.w;
        As[ac + 4][ar] = v1.x; As[ac + 5][ar] = v1.y; As[ac + 6][ar] = v1.z; As[ac + 7][ar] = v1.w;
        *reinterpret_cast<float4*>(&Bs[br][bc]) =
            *reinterpret_cast<const float4*>(&B[(size_t)(k0 + br) * NC + bn + bc]);
        *reinterpret_cast<float4*>(&Bs[br][bc + 4]) =
            *reinterpret_cast<const float4*>(&B[(size_t)(k0 + br) * NC + bn + bc + 4]);
        __syncthreads();
        #pragma unroll
        for (int k = 0; k < BK; ++k) {
            float4 a0 = *reinterpret_cast<const float4*>(&As[k][ty << 3]);
            float4 a1 = *reinterpret_cast<const float4*>(&As[k][(ty << 3) + 4]);
            float4 b0 = *reinterpret_cast<const float4*>(&Bs[k][tx << 3]);
            float4 b1 = *reinterpret_cast<const float4*>(&Bs[k][(tx << 3) + 4]);
            float av[8] = {a0.x, a0.y, a0.z, a0.w, a1.x, a1.y, a1.z, a1.w};
            float bv[8] = {b0.x, b0.y, b0.z, b0.w, b1.x, b1.y, b1.z, b1.w};
            #pragma unroll
            for (int r = 0; r < 8; ++r)
                #pragma unroll
                for (int c = 0; c < 8; ++c)
                    acc[r][c] += av[r] * bv[c];
        }
        __syncthreads();
    }
    #pragma unroll
    for (int r = 0; r < 8; ++r) {
        int row = bm + (ty << 3) + r;
        if (row < M) {
            *reinterpret_cast<float4*>(&C[(size_t)row * NC + bn + (tx << 3)]) =
                make_float4(acc[r][0], acc[r][1], acc[r][2], acc[r][3]);
            *reinterpret_cast<float4*>(&C[(size_t)row * NC + bn + (tx << 3) + 4]) =
                make_float4(acc[r][4], acc[r][5], acc[r][6], acc[r][7]);
        }
    }
}

// ---------------- attention dot products: a_src/a_dst [N,8] ----------------

template <int D>
__global__ __launch_bounds__(256) void attn_dots_kernel(const float* __restrict__ h,
                                                        const float* __restrict__ att_s,
                                                        const float* __restrict__ att_d,
                                                        float* __restrict__ a_s,
                                                        float* __restrict__ a_d, int n) {
    int gid = blockIdx.x * 256 + threadIdx.x;
    if (gid >= n * 8) return;
    int node = gid >> 3, hh = gid & 7;
    const float* hp = h + (size_t)node * 8 * D + hh * D;
    const float* as = att_s + hh * D;
    const float* ad = att_d + hh * D;
    float s1 = 0.f, s2 = 0.f;
    #pragma unroll
    for (int d = 0; d < D; d += 4) {
        float4 hv = *reinterpret_cast<const float4*>(hp + d);
        float4 av = *reinterpret_cast<const float4*>(as + d);
        float4 dv = *reinterpret_cast<const float4*>(ad + d);
        s1 += hv.x * av.x + hv.y * av.y + hv.z * av.z + hv.w * av.w;
        s2 += hv.x * dv.x + hv.y * dv.y + hv.z * dv.z + hv.w * dv.w;
    }
    a_s[gid] = s1;
    a_d[gid] = s2;
}

// ---------------- fused GAT aggregation (softmax + gather) ------------------
// C/4 lanes per node cover the whole feature row; every lane loops over all
// edges (unrolled x4 for memory-level parallelism), accumulating Sum(ev) and
// Sum(ev*h[src]). No segment max needed (logits O(1): weights *0.05),
// Sum(ev*h)/(Sum(ev)+eps) == reference alpha exactly.

#define LRELU_EXP(e) __expf((e) > 0.f ? (e) : 0.2f * (e))

template <int C, int DH>
__global__ __launch_bounds__(256) void gat_agg_kernel(const float* __restrict__ hfeat,
                                                      const float* __restrict__ a_src,
                                                      const float* __restrict__ a_dst,
                                                      const int* __restrict__ off,
                                                      const int* __restrict__ ssrc,
                                                      const float* __restrict__ bias,
                                                      float* __restrict__ outp, int n) {
    constexpr int LPN = C / 4;  // 64 (layer1) or 32 (layer2) lanes per node
    const int node = blockIdx.x * (256 / LPN) + threadIdx.x / LPN;
    if (node >= n) return;
    const int local = threadIdx.x & (LPN - 1);
    const int c0 = local * 4;
    const int h = c0 / DH;
    const float adst = a_dst[node * 8 + h];
    const int o0 = off[node], o1 = off[node + 1];
    float ax = 0.f, ay = 0.f, az = 0.f, aw = 0.f, ssum = 0.f;
    int i = o0;
    for (; i + 4 <= o1; i += 4) {
        int s0 = ssrc[i], s1 = ssrc[i + 1], s2 = ssrc[i + 2], s3 = ssrc[i + 3];
        float e0 = a_src[s0 * 8 + h], e1 = a_src[s1 * 8 + h];
        float e2 = a_src[s2 * 8 + h], e3 = a_src[s3 * 8 + h];
        float4 h0 = *reinterpret_cast<const float4*>(&hfeat[(size_t)s0 * C + c0]);
        float4 h1 = *reinterpret_cast<const float4*>(&hfeat[(size_t)s1 * C + c0]);
        float4 h2 = *reinterpret_cast<const float4*>(&hfeat[(size_t)s2 * C + c0]);
        float4 h3 = *reinterpret_cast<const float4*>(&hfeat[(size_t)s3 * C + c0]);
        float v0 = LRELU_EXP(e0 + adst), v1 = LRELU_EXP(e1 + adst);
        float v2 = LRELU_EXP(e2 + adst), v3 = LRELU_EXP(e3 + adst);
        ssum += (v0 + v1) + (v2 + v3);
        ax += v0 * h0.x + v1 * h1.x + v2 * h2.x + v3 * h3.x;
        ay += v0 * h0.y + v1 * h1.y + v2 * h2.y + v3 * h3.y;
        az += v0 * h0.z + v1 * h1.z + v2 * h2.z + v3 * h3.z;
        aw += v0 * h0.w + v1 * h1.w + v2 * h2.w + v3 * h3.w;
    }
    for (; i < o1; ++i) {
        int s = ssrc[i];
        float e = a_src[s * 8 + h] + adst;
        float v = LRELU_EXP(e);
        float4 hv = *reinterpret_cast<const float4*>(&hfeat[(size_t)s * C + c0]);
        ssum += v;
        ax += v * hv.x; ay += v * hv.y; az += v * hv.z; aw += v * hv.w;
    }
    float sinv = 1.f / (ssum + 1e-16f);
    float4 bb = *reinterpret_cast<const float4*>(bias + c0);
    float4 o;
    o.x = fmaxf(ax * sinv + bb.x, 0.f);
    o.y = fmaxf(ay * sinv + bb.y, 0.f);
    o.z = fmaxf(az * sinv + bb.z, 0.f);
    o.w = fmaxf(aw * sinv + bb.w, 0.f);
    *reinterpret_cast<float4*>(&outp[(size_t)node * C + c0]) = o;
}

// ---------------- GCN head ----------------

__global__ __launch_bounds__(256) void gcn_gemm_kernel(const float* __restrict__ A,
                                                       const float* __restrict__ Wg,
                                                       float* __restrict__ g, int n) {
    __shared__ float W[128 * 8];
    for (int i = threadIdx.x; i < 1024; i += 256) W[i] = Wg[i];
    __syncthreads();
    int gid = blockIdx.x * 256 + threadIdx.x;
    if (gid >= n * 8) return;
    int node = gid >> 3, c = gid & 7;
    const float* ap = A + (size_t)node * 128;
    float acc = 0.f;
    #pragma unroll
    for (int k = 0; k < 128; k += 4) {
        float4 av = *reinterpret_cast<const float4*>(ap + k);
        acc += av.x * W[(k + 0) * 8 + c] + av.y * W[(k + 1) * 8 + c] +
               av.z * W[(k + 2) * 8 + c] + av.w * W[(k + 3) * 8 + c];
    }
    g[gid] = acc;
}

__global__ __launch_bounds__(256) void gcn_agg_kernel(const float* __restrict__ g,
                                                      const float* __restrict__ dinv,
                                                      const int* __restrict__ off,
                                                      const int* __restrict__ ssrc,
                                                      const float* __restrict__ bg,
                                                      float* __restrict__ outp, int n) {
    int gid = blockIdx.x * 256 + threadIdx.x;
    if (gid >= n * 8) return;
    int node = gid >> 3, c = gid & 7;
    int o0 = off[node], o1 = off[node + 1];
    float acc = 0.f;
    for (int i = o0; i < o1; ++i) {
        int s = ssrc[i];
        acc += g[(size_t)s * 8 + c] * dinv[s];
    }
    outp[gid] = acc * dinv[node] + bg[c];
}

// ---------------- launch ----------------

extern "C" void kernel_launch(void* const* d_in, const int* in_sizes, int n_in,
                              void* d_out, int out_size, void* d_ws, size_t ws_size,
                              hipStream_t stream) {
    const float* x      = (const float*)d_in[0];
    const int*   ei     = (const int*)d_in[1];
    const float* W1     = (const float*)d_in[2];
    const float* att_s1 = (const float*)d_in[3];
    const float* att_d1 = (const float*)d_in[4];
    const float* b1     = (const float*)d_in[5];
    const float* W2     = (const float*)d_in[6];
    const float* att_s2 = (const float*)d_in[7];
    const float* att_d2 = (const float*)d_in[8];
    const float* b2     = (const float*)d_in[9];
    const float* Wg     = (const float*)d_in[10];
    const float* bg     = (const float*)d_in[11];
    float* out = (float*)d_out;

    const int n    = in_sizes[0] / 128;  // 50000
    const int E    = in_sizes[1] / 2;    // 500000
    const int Etot = E + n;              // 550000

    float* ws    = (float*)d_ws;
    float* h1    = ws;                           // [n,256]
    float* out1  = h1 + (size_t)n * 256;         // [n,256]
    float* h2    = h1;                           // [n,128] (h1 dead after agg1)
    float* out2  = h1 + (size_t)n * 128;         // [n,128]
    float* a_src = out1 + (size_t)n * 256;       // [n,8]
    float* a_dst = a_src + (size_t)n * 8;        // [n,8]
    float* g     = a_dst + (size_t)n * 8;        // [n,8]
    float* dinv  = g + (size_t)n * 8;            // [n]
    int*   off   = (int*)(dinv + n);             // [n+1]
    int*   deg   = off + (n + 1);                // [n]
    int*   cur   = deg + n;                      // [n]
    int*   ssrc  = cur + n;                      // [Etot]
    int*   bsum  = ssrc + Etot;                  // [<=256]

    const dim3 b256(256);
    const int nch = (n + 255) / 256;

    // CSR build
    zero_deg_kernel<<<nch, b256, 0, stream>>>(deg, n);
    hist_kernel<<<(Etot + 255) / 256, b256, 0, stream>>>(ei, E, Etot, deg);
    scanA_kernel<<<nch, b256, 0, stream>>>(deg, off, bsum, n);
    scanB_kernel<<<1, b256, 0, stream>>>(bsum, nch);
    scanC_kernel<<<nch, b256, 0, stream>>>(deg, off, bsum, cur, dinv, n);
    scatter_kernel<<<(Etot + 255) / 256, b256, 0, stream>>>(ei, E, Etot, cur, ssrc);

    // layer 1: GAT(128 -> 8x32)
    gemm_kernel<128, 256><<<dim3(2, (n + 127) / 128), b256, 0, stream>>>(x, W1, h1, n);
    attn_dots_kernel<32><<<(n * 8 + 255) / 256, b256, 0, stream>>>(h1, att_s1, att_d1, a_src, a_dst, n);
    gat_agg_kernel<256, 32><<<(n + 3) / 4, b256, 0, stream>>>(h1, a_src, a_dst, off, ssrc, b1, out1, n);

    // layer 2: GAT(256 -> 8x16)
    gemm_kernel<256, 128><<<dim3(1, (n + 127) / 128), b256, 0, stream>>>(out1, W2, h2, n);
    attn_dots_kernel<16><<<(n * 8 + 255) / 256, b256, 0, stream>>>(h2, att_s2, att_d2, a_src, a_dst, n);
    gat_agg_kernel<128, 16><<<(n + 7) / 8, b256, 0, stream>>>(h2, a_src, a_dst, off, ssrc, b2, out2, n);

    // GCN head
    gcn_gemm_kernel<<<(n * 8 + 255) / 256, b256, 0, stream>>>(out2, Wg, g, n);
    gcn_agg_kernel<<<(n * 8 + 255) / 256, b256, 0, stream>>>(g, dinv, off, ssrc, bg, out, n);
}

// Round 5
// 333.317 us; speedup vs baseline: 1.2697x; 1.2114x over previous
//
#include <hip/hip_runtime.h>
#include <hip/hip_bf16.h>

// ---------------------------------------------------------------------------
// GATsmall: 2x GATConv (8 heads) + GCNConv head. N=50000, E=500000 (+N self
// loops). Round 5: bf16 gather tables (h1/h2) halve gather traffic; attention
// dots computed exactly in fp32 via factored weights a = x @ (W @ att), so
// the bf16 rounding never touches the softmax logits. Fused softmax+gather
// agg (64-lane/node, 4x unroll), 128x128 fp32 GEMM with bf16 output epilogue.
// ---------------------------------------------------------------------------

// ---------------- CSR build ----------------

__global__ __launch_bounds__(256) void zero_deg_kernel(int* __restrict__ deg, int n) {
    int i = blockIdx.x * 256 + threadIdx.x;
    if (i < n) deg[i] = 0;
}

__global__ __launch_bounds__(256) void hist_kernel(const int* __restrict__ ei, int E, int Etot,
                                                   int* __restrict__ deg) {
    int e = blockIdx.x * 256 + threadIdx.x;
    if (e >= Etot) return;
    int d = (e < E) ? ei[E + e] : (e - E);  // tail = self loops
    atomicAdd(&deg[d], 1);
}

__global__ __launch_bounds__(256) void scanA_kernel(const int* __restrict__ deg,
                                                    int* __restrict__ off,
                                                    int* __restrict__ bsum, int n) {
    __shared__ int buf[256];
    int t = threadIdx.x;
    int i = blockIdx.x * 256 + t;
    int v = (i < n) ? deg[i] : 0;
    buf[t] = v;
    __syncthreads();
    #pragma unroll
    for (int st = 1; st < 256; st <<= 1) {
        int x = (t >= st) ? buf[t - st] : 0;
        __syncthreads();
        buf[t] += x;
        __syncthreads();
    }
    if (i < n) off[i + 1] = buf[t];
    if (t == 255) bsum[blockIdx.x] = buf[255];
}

__global__ __launch_bounds__(256) void scanB_kernel(int* __restrict__ bsum, int nb) {
    __shared__ int buf[256];
    int t = threadIdx.x;
    int v = (t < nb) ? bsum[t] : 0;
    buf[t] = v;
    __syncthreads();
    #pragma unroll
    for (int st = 1; st < 256; st <<= 1) {
        int x = (t >= st) ? buf[t - st] : 0;
        __syncthreads();
        buf[t] += x;
        __syncthreads();
    }
    if (t < nb) bsum[t] = buf[t] - v;  // exclusive prefix of chunk sums
}

// also computes dinv for the GCN head (deg is final here)
__global__ __launch_bounds__(256) void scanC_kernel(const int* __restrict__ deg,
                                                    int* __restrict__ off,
                                                    const int* __restrict__ bsum,
                                                    int* __restrict__ cur,
                                                    float* __restrict__ dinv, int n) {
    int i = blockIdx.x * 256 + threadIdx.x;
    if (i < n) {
        int o = off[i + 1] + bsum[blockIdx.x];
        off[i + 1] = o;
        cur[i] = o - deg[i];
        dinv[i] = rsqrtf((float)deg[i]);  // deg >= 1 (self loop)
    }
    if (i == 0) off[0] = 0;
}

__global__ __launch_bounds__(256) void scatter_kernel(const int* __restrict__ ei, int E, int Etot,
                                                      int* __restrict__ cur,
                                                      int* __restrict__ ssrc) {
    int e = blockIdx.x * 256 + threadIdx.x;
    if (e >= Etot) return;
    int s, d;
    if (e < E) { s = ei[e]; d = ei[E + e]; }
    else       { s = e - E; d = e - E; }
    int pos = atomicAdd(&cur[d], 1);
    ssrc[pos] = s;
}

// ---------------- factored attention weights: w[k][h] = W[k,:] . att[h] -----

template <int K, int D>
__global__ __launch_bounds__(256) void wprep_kernel(const float* __restrict__ W,
                                                    const float* __restrict__ att_s,
                                                    const float* __restrict__ att_d,
                                                    float* __restrict__ ws,
                                                    float* __restrict__ wd) {
    int t = blockIdx.x * 256 + threadIdx.x;  // t = k*8 + h
    if (t >= K * 8) return;
    int k = t >> 3, h = t & 7;
    const float* wrow = W + (size_t)k * (8 * D) + h * D;
    const float* as = att_s + h * D;
    const float* ad = att_d + h * D;
    float s1 = 0.f, s2 = 0.f;
    #pragma unroll
    for (int d = 0; d < D; d += 4) {
        float4 wv = *reinterpret_cast<const float4*>(wrow + d);
        float4 av = *reinterpret_cast<const float4*>(as + d);
        float4 dv = *reinterpret_cast<const float4*>(ad + d);
        s1 += wv.x * av.x + wv.y * av.y + wv.z * av.z + wv.w * av.w;
        s2 += wv.x * dv.x + wv.y * dv.y + wv.z * dv.z + wv.w * dv.w;
    }
    ws[t] = s1;
    wd[t] = s2;
}

// a_s[n][8], a_d[n][8] = X[n,K] @ ws/wd[K,8]  (fp32 exact attention logits)
template <int K>
__global__ __launch_bounds__(256) void adots_kernel(const float* __restrict__ X,
                                                    const float* __restrict__ ws,
                                                    const float* __restrict__ wd,
                                                    float* __restrict__ a_s,
                                                    float* __restrict__ a_d, int n) {
    int gid = blockIdx.x * 256 + threadIdx.x;
    if (gid >= n * 8) return;
    int node = gid >> 3, h = gid & 7;
    const float* xp = X + (size_t)node * K;
    float s1 = 0.f, s2 = 0.f;
    #pragma unroll 4
    for (int k = 0; k < K; k += 4) {
        float4 xv = *reinterpret_cast<const float4*>(xp + k);
        s1 += xv.x * ws[(k + 0) * 8 + h] + xv.y * ws[(k + 1) * 8 + h] +
              xv.z * ws[(k + 2) * 8 + h] + xv.w * ws[(k + 3) * 8 + h];
        s2 += xv.x * wd[(k + 0) * 8 + h] + xv.y * wd[(k + 1) * 8 + h] +
              xv.z * wd[(k + 2) * 8 + h] + xv.w * wd[(k + 3) * 8 + h];
    }
    a_s[gid] = s1;
    a_d[gid] = s2;
}

// ---------------- fp32 tiled GEMM: C[M,NC] = A[M,K] @ B[K,NC] ----------------
// BM=BN=128, BK=16, 256 threads, 8x8 per-thread micro-tile; optional bf16 out.

template <int K, int NC, bool BF16OUT>
__global__ __launch_bounds__(256) void gemm_kernel(const float* __restrict__ A,
                                                   const float* __restrict__ B,
                                                   void* __restrict__ Cv, int M) {
    constexpr int BK = 16;
    __shared__ float As[BK][132];
    __shared__ float Bs[BK][128];
    const int tid = threadIdx.x;
    const int bm = blockIdx.y * 128;
    const int bn = blockIdx.x * 128;
    const int ty = tid >> 4;          // 0..15 -> 8 rows
    const int tx = tid & 15;          // 0..15 -> 8 cols
    const int ar = tid >> 1;          // 0..127
    const int ac = (tid & 1) << 3;    // 0 or 8
    const int br = tid >> 4;          // 0..15
    const int bc = (tid & 15) << 3;   // 0..120
    float acc[8][8] = {};
    for (int k0 = 0; k0 < K; k0 += BK) {
        int row = bm + ar;
        float4 v0 = make_float4(0.f, 0.f, 0.f, 0.f);
        float4 v1 = make_float4(0.f, 0.f, 0.f, 0.f);
        if (row < M) {
            v0 = *reinterpret_cast<const float4*>(&A[(size_t)row * K + k0 + ac]);
            v1 = *reinterpret_cast<const float4*>(&A[(size_t)row * K + k0 + ac + 4]);
        }
        As[ac + 0][ar] = v0.x; As[ac + 1][ar] = v0.y; As[ac + 2][ar] = v0.z; As[ac + 3][ar] = v0.w;
        As[ac + 4][ar] = v1.x; As[ac + 5][ar] = v1.y; As[ac + 6][ar] = v1.z; As[ac + 7][ar] = v1.w;
        *reinterpret_cast<float4*>(&Bs[br][bc]) =
            *reinterpret_cast<const float4*>(&B[(size_t)(k0 + br) * NC + bn + bc]);
        *reinterpret_cast<float4*>(&Bs[br][bc + 4]) =
            *reinterpret_cast<const float4*>(&B[(size_t)(k0 + br) * NC + bn + bc + 4]);
        __syncthreads();
        #pragma unroll
        for (int k = 0; k < BK; ++k) {
            float4 a0 = *reinterpret_cast<const float4*>(&As[k][ty << 3]);
            float4 a1 = *reinterpret_cast<const float4*>(&As[k][(ty << 3) + 4]);
            float4 b0 = *reinterpret_cast<const float4*>(&Bs[k][tx << 3]);
            float4 b1 = *reinterpret_cast<const float4*>(&Bs[k][(tx << 3) + 4]);
            float av[8] = {a0.x, a0.y, a0.z, a0.w, a1.x, a1.y, a1.z, a1.w};
            float bv[8] = {b0.x, b0.y, b0.z, b0.w, b1.x, b1.y, b1.z, b1.w};
            #pragma unroll
            for (int r = 0; r < 8; ++r)
                #pragma unroll
                for (int c = 0; c < 8; ++c)
                    acc[r][c] += av[r] * bv[c];
        }
        __syncthreads();
    }
    #pragma unroll
    for (int r = 0; r < 8; ++r) {
        int row = bm + (ty << 3) + r;
        if (row >= M) continue;
        if constexpr (BF16OUT) {
            ushort u[8];
            #pragma unroll
            for (int c = 0; c < 8; ++c) {
                __hip_bfloat16 hb = __float2bfloat16(acc[r][c]);
                u[c] = *reinterpret_cast<ushort*>(&hb);
            }
            *reinterpret_cast<uint4*>(&((ushort*)Cv)[(size_t)row * NC + bn + (tx << 3)]) =
                *reinterpret_cast<uint4*>(u);
        } else {
            float* C = (float*)Cv;
            *reinterpret_cast<float4*>(&C[(size_t)row * NC + bn + (tx << 3)]) =
                make_float4(acc[r][0], acc[r][1], acc[r][2], acc[r][3]);
            *reinterpret_cast<float4*>(&C[(size_t)row * NC + bn + (tx << 3) + 4]) =
                make_float4(acc[r][4], acc[r][5], acc[r][6], acc[r][7]);
        }
    }
}

// ---------------- fused GAT aggregation (softmax + bf16 gather) -------------
// C/4 lanes per node cover the feature row (8B bf16x4 per lane); every lane
// loops over all edges (x4 unroll), accumulating Sum(ev) and Sum(ev*h[src])
// in fp32. Logits from exact fp32 a_s/a_d. Sum(ev*h)/(Sum(ev)+eps) == ref.

#define LRELU_EXP(e) __expf((e) > 0.f ? (e) : 0.2f * (e))

__device__ __forceinline__ float4 bf4_to_f4(uint2 v) {
    float4 r;
    r.x = __uint_as_float((v.x & 0xFFFFu) << 16);
    r.y = __uint_as_float(v.x & 0xFFFF0000u);
    r.z = __uint_as_float((v.y & 0xFFFFu) << 16);
    r.w = __uint_as_float(v.y & 0xFFFF0000u);
    return r;
}

template <int C, int DH>
__global__ __launch_bounds__(256) void gat_agg_kernel(const ushort* __restrict__ hfeat,
                                                      const float* __restrict__ a_src,
                                                      const float* __restrict__ a_dst,
                                                      const int* __restrict__ off,
                                                      const int* __restrict__ ssrc,
                                                      const float* __restrict__ bias,
                                                      float* __restrict__ outp, int n) {
    constexpr int LPN = C / 4;  // 64 (layer1) or 32 (layer2) lanes per node
    const int node = blockIdx.x * (256 / LPN) + threadIdx.x / LPN;
    if (node >= n) return;
    const int local = threadIdx.x & (LPN - 1);
    const int c0 = local * 4;
    const int h = c0 / DH;
    const float adst = a_dst[node * 8 + h];
    const int o0 = off[node], o1 = off[node + 1];
    float ax = 0.f, ay = 0.f, az = 0.f, aw = 0.f, ssum = 0.f;
    int i = o0;
    for (; i + 4 <= o1; i += 4) {
        int s0 = ssrc[i], s1 = ssrc[i + 1], s2 = ssrc[i + 2], s3 = ssrc[i + 3];
        float e0 = a_src[s0 * 8 + h], e1 = a_src[s1 * 8 + h];
        float e2 = a_src[s2 * 8 + h], e3 = a_src[s3 * 8 + h];
        uint2 r0 = *reinterpret_cast<const uint2*>(&hfeat[(size_t)s0 * C + c0]);
        uint2 r1 = *reinterpret_cast<const uint2*>(&hfeat[(size_t)s1 * C + c0]);
        uint2 r2 = *reinterpret_cast<const uint2*>(&hfeat[(size_t)s2 * C + c0]);
        uint2 r3 = *reinterpret_cast<const uint2*>(&hfeat[(size_t)s3 * C + c0]);
        float4 h0 = bf4_to_f4(r0), h1 = bf4_to_f4(r1), h2 = bf4_to_f4(r2), h3 = bf4_to_f4(r3);
        float v0 = LRELU_EXP(e0 + adst), v1 = LRELU_EXP(e1 + adst);
        float v2 = LRELU_EXP(e2 + adst), v3 = LRELU_EXP(e3 + adst);
        ssum += (v0 + v1) + (v2 + v3);
        ax += v0 * h0.x + v1 * h1.x + v2 * h2.x + v3 * h3.x;
        ay += v0 * h0.y + v1 * h1.y + v2 * h2.y + v3 * h3.y;
        az += v0 * h0.z + v1 * h1.z + v2 * h2.z + v3 * h3.z;
        aw += v0 * h0.w + v1 * h1.w + v2 * h2.w + v3 * h3.w;
    }
    for (; i < o1; ++i) {
        int s = ssrc[i];
        float e = a_src[s * 8 + h] + adst;
        float v = LRELU_EXP(e);
        uint2 rv = *reinterpret_cast<const uint2*>(&hfeat[(size_t)s * C + c0]);
        float4 hv = bf4_to_f4(rv);
        ssum += v;
        ax += v * hv.x; ay += v * hv.y; az += v * hv.z; aw += v * hv.w;
    }
    float sinv = 1.f / (ssum + 1e-16f);
    float4 bb = *reinterpret_cast<const float4*>(bias + c0);
    float4 o;
    o.x = fmaxf(ax * sinv + bb.x, 0.f);
    o.y = fmaxf(ay * sinv + bb.y, 0.f);
    o.z = fmaxf(az * sinv + bb.z, 0.f);
    o.w = fmaxf(aw * sinv + bb.w, 0.f);
    *reinterpret_cast<float4*>(&outp[(size_t)node * C + c0]) = o;
}

// ---------------- GCN head ----------------

__global__ __launch_bounds__(256) void gcn_gemm_kernel(const float* __restrict__ A,
                                                       const float* __restrict__ Wg,
                                                       float* __restrict__ g, int n) {
    __shared__ float W[128 * 8];
    for (int i = threadIdx.x; i < 1024; i += 256) W[i] = Wg[i];
    __syncthreads();
    int gid = blockIdx.x * 256 + threadIdx.x;
    if (gid >= n * 8) return;
    int node = gid >> 3, c = gid & 7;
    const float* ap = A + (size_t)node * 128;
    float acc = 0.f;
    #pragma unroll
    for (int k = 0; k < 128; k += 4) {
        float4 av = *reinterpret_cast<const float4*>(ap + k);
        acc += av.x * W[(k + 0) * 8 + c] + av.y * W[(k + 1) * 8 + c] +
               av.z * W[(k + 2) * 8 + c] + av.w * W[(k + 3) * 8 + c];
    }
    g[gid] = acc;
}

__global__ __launch_bounds__(256) void gcn_agg_kernel(const float* __restrict__ g,
                                                      const float* __restrict__ dinv,
                                                      const int* __restrict__ off,
                                                      const int* __restrict__ ssrc,
                                                      const float* __restrict__ bg,
                                                      float* __restrict__ outp, int n) {
    int gid = blockIdx.x * 256 + threadIdx.x;
    if (gid >= n * 8) return;
    int node = gid >> 3, c = gid & 7;
    int o0 = off[node], o1 = off[node + 1];
    float acc = 0.f;
    for (int i = o0; i < o1; ++i) {
        int s = ssrc[i];
        acc += g[(size_t)s * 8 + c] * dinv[s];
    }
    outp[gid] = acc * dinv[node] + bg[c];
}

// ---------------- launch ----------------

extern "C" void kernel_launch(void* const* d_in, const int* in_sizes, int n_in,
                              void* d_out, int out_size, void* d_ws, size_t ws_size,
                              hipStream_t stream) {
    const float* x      = (const float*)d_in[0];
    const int*   ei     = (const int*)d_in[1];
    const float* W1     = (const float*)d_in[2];
    const float* att_s1 = (const float*)d_in[3];
    const float* att_d1 = (const float*)d_in[4];
    const float* b1     = (const float*)d_in[5];
    const float* W2     = (const float*)d_in[6];
    const float* att_s2 = (const float*)d_in[7];
    const float* att_d2 = (const float*)d_in[8];
    const float* b2     = (const float*)d_in[9];
    const float* Wg     = (const float*)d_in[10];
    const float* bg     = (const float*)d_in[11];
    float* out = (float*)d_out;

    const int n    = in_sizes[0] / 128;  // 50000
    const int E    = in_sizes[1] / 2;    // 500000
    const int Etot = E + n;              // 550000

    // workspace carve-up (~125 MB)
    float*  ws   = (float*)d_ws;
    ushort* h1b  = (ushort*)ws;                  // [n,256] bf16 = n*128 float slots
    float*  out1 = ws + (size_t)n * 128;         // [n,256] fp32
    ushort* h2b  = (ushort*)(out1 + (size_t)n * 256);  // [n,128] bf16 = n*64 slots
    float*  out2 = out1 + (size_t)n * 256 + (size_t)n * 64;  // [n,128] fp32
    float*  a_s  = out2 + (size_t)n * 128;       // [n,8]
    float*  a_d  = a_s + (size_t)n * 8;          // [n,8]
    float*  g    = a_d + (size_t)n * 8;          // [n,8]
    float*  dinv = g + (size_t)n * 8;            // [n]
    float*  ws1  = dinv + n;                     // [128*8]
    float*  wd1  = ws1 + 1024;                   // [128*8]
    float*  ws2  = wd1 + 1024;                   // [256*8]
    float*  wd2  = ws2 + 2048;                   // [256*8]
    int*    off  = (int*)(wd2 + 2048);           // [n+1]
    int*    deg  = off + (n + 1);                // [n]
    int*    cur  = deg + n;                      // [n]
    int*    ssrc = cur + n;                      // [Etot]
    int*    bsum = ssrc + Etot;                  // [<=256]

    const dim3 b256(256);
    const int nch = (n + 255) / 256;

    // CSR build
    zero_deg_kernel<<<nch, b256, 0, stream>>>(deg, n);
    hist_kernel<<<(Etot + 255) / 256, b256, 0, stream>>>(ei, E, Etot, deg);
    scanA_kernel<<<nch, b256, 0, stream>>>(deg, off, bsum, n);
    scanB_kernel<<<1, b256, 0, stream>>>(bsum, nch);
    scanC_kernel<<<nch, b256, 0, stream>>>(deg, off, bsum, cur, dinv, n);
    scatter_kernel<<<(Etot + 255) / 256, b256, 0, stream>>>(ei, E, Etot, cur, ssrc);

    // factored attention weights (tiny)
    wprep_kernel<128, 32><<<4, b256, 0, stream>>>(W1, att_s1, att_d1, ws1, wd1);
    wprep_kernel<256, 16><<<8, b256, 0, stream>>>(W2, att_s2, att_d2, ws2, wd2);

    // layer 1: GAT(128 -> 8x32)
    adots_kernel<128><<<(n * 8 + 255) / 256, b256, 0, stream>>>(x, ws1, wd1, a_s, a_d, n);
    gemm_kernel<128, 256, true><<<dim3(2, (n + 127) / 128), b256, 0, stream>>>(x, W1, h1b, n);
    gat_agg_kernel<256, 32><<<(n + 3) / 4, b256, 0, stream>>>(h1b, a_s, a_d, off, ssrc, b1, out1, n);

    // layer 2: GAT(256 -> 8x16)
    adots_kernel<256><<<(n * 8 + 255) / 256, b256, 0, stream>>>(out1, ws2, wd2, a_s, a_d, n);
    gemm_kernel<256, 128, true><<<dim3(1, (n + 127) / 128), b256, 0, stream>>>(out1, W2, h2b, n);
    gat_agg_kernel<128, 16><<<(n + 7) / 8, b256, 0, stream>>>(h2b, a_s, a_d, off, ssrc, b2, out2, n);

    // GCN head
    gcn_gemm_kernel<<<(n * 8 + 255) / 256, b256, 0, stream>>>(out2, Wg, g, n);
    gcn_agg_kernel<<<(n * 8 + 255) / 256, b256, 0, stream>>>(g, dinv, off, ssrc, bg, out, n);
}

// Round 6
// 280.769 us; speedup vs baseline: 1.5073x; 1.1872x over previous
//
#include <hip/hip_runtime.h>
#include <hip/hip_bf16.h>

// ---------------------------------------------------------------------------
// GATsmall: 2x GATConv (8 heads) + GCNConv head. N=50000, E=500000 (+N self
// loops). Round 6: bf16 MFMA GEMMs (16x16x32, fp32 accum) replace fp32 VALU
// GEMMs; attention logits stay fp32-exact via factored a = x @ (W @ att).
// Fused softmax+gather agg on bf16 tables (unchanged from R5).
// ---------------------------------------------------------------------------

typedef __attribute__((ext_vector_type(8))) short bf16x8;
typedef __attribute__((ext_vector_type(4))) float f32x4;

// ---------------- CSR build ----------------

__global__ __launch_bounds__(256) void zero_deg_kernel(int* __restrict__ deg, int n) {
    int i = blockIdx.x * 256 + threadIdx.x;
    if (i < n) deg[i] = 0;
}

__global__ __launch_bounds__(256) void hist_kernel(const int* __restrict__ ei, int E, int Etot,
                                                   int* __restrict__ deg) {
    int e = blockIdx.x * 256 + threadIdx.x;
    if (e >= Etot) return;
    int d = (e < E) ? ei[E + e] : (e - E);  // tail = self loops
    atomicAdd(&deg[d], 1);
}

__global__ __launch_bounds__(256) void scanA_kernel(const int* __restrict__ deg,
                                                    int* __restrict__ off,
                                                    int* __restrict__ bsum, int n) {
    __shared__ int buf[256];
    int t = threadIdx.x;
    int i = blockIdx.x * 256 + t;
    int v = (i < n) ? deg[i] : 0;
    buf[t] = v;
    __syncthreads();
    #pragma unroll
    for (int st = 1; st < 256; st <<= 1) {
        int x = (t >= st) ? buf[t - st] : 0;
        __syncthreads();
        buf[t] += x;
        __syncthreads();
    }
    if (i < n) off[i + 1] = buf[t];
    if (t == 255) bsum[blockIdx.x] = buf[255];
}

__global__ __launch_bounds__(256) void scanB_kernel(int* __restrict__ bsum, int nb) {
    __shared__ int buf[256];
    int t = threadIdx.x;
    int v = (t < nb) ? bsum[t] : 0;
    buf[t] = v;
    __syncthreads();
    #pragma unroll
    for (int st = 1; st < 256; st <<= 1) {
        int x = (t >= st) ? buf[t - st] : 0;
        __syncthreads();
        buf[t] += x;
        __syncthreads();
    }
    if (t < nb) bsum[t] = buf[t] - v;  // exclusive prefix of chunk sums
}

__global__ __launch_bounds__(256) void scanC_kernel(const int* __restrict__ deg,
                                                    int* __restrict__ off,
                                                    const int* __restrict__ bsum,
                                                    int* __restrict__ cur,
                                                    float* __restrict__ dinv, int n) {
    int i = blockIdx.x * 256 + threadIdx.x;
    if (i < n) {
        int o = off[i + 1] + bsum[blockIdx.x];
        off[i + 1] = o;
        cur[i] = o - deg[i];
        dinv[i] = rsqrtf((float)deg[i]);  // deg >= 1 (self loop)
    }
    if (i == 0) off[0] = 0;
}

__global__ __launch_bounds__(256) void scatter_kernel(const int* __restrict__ ei, int E, int Etot,
                                                      int* __restrict__ cur,
                                                      int* __restrict__ ssrc) {
    int e = blockIdx.x * 256 + threadIdx.x;
    if (e >= Etot) return;
    int s, d;
    if (e < E) { s = ei[e]; d = ei[E + e]; }
    else       { s = e - E; d = e - E; }
    int pos = atomicAdd(&cur[d], 1);
    ssrc[pos] = s;
}

// ---------------- fp32 -> bf16 converts / weight transpose ----------------

__global__ __launch_bounds__(256) void cvt_bf16_kernel(const float* __restrict__ in,
                                                       ushort* __restrict__ outb, int count) {
    int i = (blockIdx.x * 256 + threadIdx.x) * 4;
    if (i >= count) return;
    float4 v = *reinterpret_cast<const float4*>(in + i);
    ushort4 u;
    __hip_bfloat16 b0 = __float2bfloat16(v.x); u.x = *reinterpret_cast<ushort*>(&b0);
    __hip_bfloat16 b1 = __float2bfloat16(v.y); u.y = *reinterpret_cast<ushort*>(&b1);
    __hip_bfloat16 b2 = __float2bfloat16(v.z); u.z = *reinterpret_cast<ushort*>(&b2);
    __hip_bfloat16 b3 = __float2bfloat16(v.w); u.w = *reinterpret_cast<ushort*>(&b3);
    *reinterpret_cast<ushort4*>(outb + i) = u;
}

// W [K][NC] fp32 -> Wt [NC][K] bf16
template <int K, int NC>
__global__ __launch_bounds__(256) void wtrans_kernel(const float* __restrict__ W,
                                                     ushort* __restrict__ Wt) {
    int t = blockIdx.x * 256 + threadIdx.x;  // t = nidx*K + k
    if (t >= K * NC) return;
    int nn = t / K, k = t % K;
    __hip_bfloat16 b = __float2bfloat16(W[(size_t)k * NC + nn]);
    Wt[t] = *reinterpret_cast<ushort*>(&b);
}

// ---------------- factored attention weights: w[k][h] = W[k,:] . att[h] -----

template <int K, int D>
__global__ __launch_bounds__(256) void wprep_kernel(const float* __restrict__ W,
                                                    const float* __restrict__ att_s,
                                                    const float* __restrict__ att_d,
                                                    float* __restrict__ ws,
                                                    float* __restrict__ wd) {
    int t = blockIdx.x * 256 + threadIdx.x;  // t = k*8 + h
    if (t >= K * 8) return;
    int k = t >> 3, h = t & 7;
    const float* wrow = W + (size_t)k * (8 * D) + h * D;
    const float* as = att_s + h * D;
    const float* ad = att_d + h * D;
    float s1 = 0.f, s2 = 0.f;
    #pragma unroll
    for (int d = 0; d < D; d += 4) {
        float4 wv = *reinterpret_cast<const float4*>(wrow + d);
        float4 av = *reinterpret_cast<const float4*>(as + d);
        float4 dv = *reinterpret_cast<const float4*>(ad + d);
        s1 += wv.x * av.x + wv.y * av.y + wv.z * av.z + wv.w * av.w;
        s2 += wv.x * dv.x + wv.y * dv.y + wv.z * dv.z + wv.w * dv.w;
    }
    ws[t] = s1;
    wd[t] = s2;
}

// a_s[n][8], a_d[n][8] = X[n,K] @ ws/wd[K,8]  (fp32 exact attention logits)
template <int K>
__global__ __launch_bounds__(256) void adots_kernel(const float* __restrict__ X,
                                                    const float* __restrict__ ws,
                                                    const float* __restrict__ wd,
                                                    float* __restrict__ a_s,
                                                    float* __restrict__ a_d, int n) {
    int gid = blockIdx.x * 256 + threadIdx.x;
    if (gid >= n * 8) return;
    int node = gid >> 3, h = gid & 7;
    const float* xp = X + (size_t)node * K;
    float s1 = 0.f, s2 = 0.f;
    #pragma unroll 4
    for (int k = 0; k < K; k += 4) {
        float4 xv = *reinterpret_cast<const float4*>(xp + k);
        s1 += xv.x * ws[(k + 0) * 8 + h] + xv.y * ws[(k + 1) * 8 + h] +
              xv.z * ws[(k + 2) * 8 + h] + xv.w * ws[(k + 3) * 8 + h];
        s2 += xv.x * wd[(k + 0) * 8 + h] + xv.y * wd[(k + 1) * 8 + h] +
              xv.z * wd[(k + 2) * 8 + h] + xv.w * wd[(k + 3) * 8 + h];
    }
    a_s[gid] = s1;
    a_d[gid] = s2;
}

// ---------------- bf16 MFMA GEMM: Cb[M,NC] = Ab[M,K] @ Bt[NC,K]^T -----------
// BM=128, BN=128|64, BK=32. 4 waves in 2x2; each wave owns 64 x BN/2, i.e.
// 4 x FN fragments of 16x16. mfma_f32_16x16x32_bf16: a lane&15 = m (k along
// lane>>4 chunk), b lane&15 = n; D: row=(lane>>4)*4+reg, col=lane&15
// (guide-verified m89/m91). LDS [row][32 bf16] linear: 64B row stride gives
// balanced 8 chunks / 4-bank group on frag b128 reads (no swizzle needed).

template <int K, int NC, int BN>
__global__ __launch_bounds__(256) void mfma_gemm_kernel(const ushort* __restrict__ Ab,
                                                        const ushort* __restrict__ Bt,
                                                        ushort* __restrict__ Cb, int M) {
    constexpr int BM = 128, BK = 32;
    constexpr int FN = BN / 32;
    __shared__ ushort As[BM * BK];
    __shared__ ushort Bs[BN * BK];
    const int tid = threadIdx.x;
    const int lane = tid & 63;
    const int wid = tid >> 6;
    const int bm = blockIdx.y * BM;
    const int bn = blockIdx.x * BN;
    const int wm = (wid >> 1) * 64;
    const int wn = (wid & 1) * (BN / 2);
    const int l15 = lane & 15;
    const int l4 = lane >> 4;
    f32x4 zero4 = {0.f, 0.f, 0.f, 0.f};
    f32x4 acc[4][FN];
    #pragma unroll
    for (int i = 0; i < 4; ++i)
        #pragma unroll
        for (int j = 0; j < FN; ++j) acc[i][j] = zero4;

    for (int k0 = 0; k0 < K; k0 += BK) {
        // stage A tile (128x32 bf16): 512 16B-chunks, 2 per thread, coalesced
        #pragma unroll
        for (int p = 0; p < 2; ++p) {
            int ci = tid + p * 256;
            int r = ci >> 2, c = ci & 3;
            int row = bm + r;
            uint4 v = make_uint4(0, 0, 0, 0);
            if (row < M) v = *reinterpret_cast<const uint4*>(&Ab[(size_t)row * K + k0 + c * 8]);
            *reinterpret_cast<uint4*>(&As[r * BK + c * 8]) = v;
        }
        // stage B tile (BNx32 bf16) from transposed weights (always in-range)
        #pragma unroll
        for (int p = 0; p < BN / 64; ++p) {
            int ci = tid + p * 256;
            int r = ci >> 2, c = ci & 3;
            uint4 v = *reinterpret_cast<const uint4*>(&Bt[(size_t)(bn + r) * K + k0 + c * 8]);
            *reinterpret_cast<uint4*>(&Bs[r * BK + c * 8]) = v;
        }
        __syncthreads();
        bf16x8 af[4], bfr[FN];
        #pragma unroll
        for (int i = 0; i < 4; ++i)
            af[i] = *reinterpret_cast<const bf16x8*>(&As[(wm + 16 * i + l15) * BK + l4 * 8]);
        #pragma unroll
        for (int j = 0; j < FN; ++j)
            bfr[j] = *reinterpret_cast<const bf16x8*>(&Bs[(wn + 16 * j + l15) * BK + l4 * 8]);
        #pragma unroll
        for (int i = 0; i < 4; ++i)
            #pragma unroll
            for (int j = 0; j < FN; ++j)
                acc[i][j] = __builtin_amdgcn_mfma_f32_16x16x32_bf16(af[i], bfr[j], acc[i][j], 0, 0, 0);
        __syncthreads();
    }
    // epilogue: D row = (lane>>4)*4 + reg, col = lane&15
    #pragma unroll
    for (int i = 0; i < 4; ++i) {
        #pragma unroll
        for (int p = 0; p < 4; ++p) {
            int row = bm + wm + 16 * i + l4 * 4 + p;
            if (row < M) {
                #pragma unroll
                for (int j = 0; j < FN; ++j) {
                    __hip_bfloat16 hb = __float2bfloat16(acc[i][j][p]);
                    Cb[(size_t)row * NC + bn + wn + 16 * j + l15] = *reinterpret_cast<ushort*>(&hb);
                }
            }
        }
    }
}

// ---------------- fused GAT aggregation (softmax + bf16 gather) -------------

#define LRELU_EXP(e) __expf((e) > 0.f ? (e) : 0.2f * (e))

__device__ __forceinline__ float4 bf4_to_f4(uint2 v) {
    float4 r;
    r.x = __uint_as_float((v.x & 0xFFFFu) << 16);
    r.y = __uint_as_float(v.x & 0xFFFF0000u);
    r.z = __uint_as_float((v.y & 0xFFFFu) << 16);
    r.w = __uint_as_float(v.y & 0xFFFF0000u);
    return r;
}

template <int C, int DH, bool DUAL>
__global__ __launch_bounds__(256) void gat_agg_kernel(const ushort* __restrict__ hfeat,
                                                      const float* __restrict__ a_src,
                                                      const float* __restrict__ a_dst,
                                                      const int* __restrict__ off,
                                                      const int* __restrict__ ssrc,
                                                      const float* __restrict__ bias,
                                                      float* __restrict__ outp,
                                                      ushort* __restrict__ outb, int n) {
    constexpr int LPN = C / 4;  // 64 (layer1) or 32 (layer2) lanes per node
    const int node = blockIdx.x * (256 / LPN) + threadIdx.x / LPN;
    if (node >= n) return;
    const int local = threadIdx.x & (LPN - 1);
    const int c0 = local * 4;
    const int h = c0 / DH;
    const float adst = a_dst[node * 8 + h];
    const int o0 = off[node], o1 = off[node + 1];
    float ax = 0.f, ay = 0.f, az = 0.f, aw = 0.f, ssum = 0.f;
    int i = o0;
    for (; i + 4 <= o1; i += 4) {
        int s0 = ssrc[i], s1 = ssrc[i + 1], s2 = ssrc[i + 2], s3 = ssrc[i + 3];
        float e0 = a_src[s0 * 8 + h], e1 = a_src[s1 * 8 + h];
        float e2 = a_src[s2 * 8 + h], e3 = a_src[s3 * 8 + h];
        uint2 r0 = *reinterpret_cast<const uint2*>(&hfeat[(size_t)s0 * C + c0]);
        uint2 r1 = *reinterpret_cast<const uint2*>(&hfeat[(size_t)s1 * C + c0]);
        uint2 r2 = *reinterpret_cast<const uint2*>(&hfeat[(size_t)s2 * C + c0]);
        uint2 r3 = *reinterpret_cast<const uint2*>(&hfeat[(size_t)s3 * C + c0]);
        float4 h0 = bf4_to_f4(r0), h1 = bf4_to_f4(r1), h2 = bf4_to_f4(r2), h3 = bf4_to_f4(r3);
        float v0 = LRELU_EXP(e0 + adst), v1 = LRELU_EXP(e1 + adst);
        float v2 = LRELU_EXP(e2 + adst), v3 = LRELU_EXP(e3 + adst);
        ssum += (v0 + v1) + (v2 + v3);
        ax += v0 * h0.x + v1 * h1.x + v2 * h2.x + v3 * h3.x;
        ay += v0 * h0.y + v1 * h1.y + v2 * h2.y + v3 * h3.y;
        az += v0 * h0.z + v1 * h1.z + v2 * h2.z + v3 * h3.z;
        aw += v0 * h0.w + v1 * h1.w + v2 * h2.w + v3 * h3.w;
    }
    for (; i < o1; ++i) {
        int s = ssrc[i];
        float e = a_src[s * 8 + h] + adst;
        float v = LRELU_EXP(e);
        uint2 rv = *reinterpret_cast<const uint2*>(&hfeat[(size_t)s * C + c0]);
        float4 hv = bf4_to_f4(rv);
        ssum += v;
        ax += v * hv.x; ay += v * hv.y; az += v * hv.z; aw += v * hv.w;
    }
    float sinv = 1.f / (ssum + 1e-16f);
    float4 bb = *reinterpret_cast<const float4*>(bias + c0);
    float4 o;
    o.x = fmaxf(ax * sinv + bb.x, 0.f);
    o.y = fmaxf(ay * sinv + bb.y, 0.f);
    o.z = fmaxf(az * sinv + bb.z, 0.f);
    o.w = fmaxf(aw * sinv + bb.w, 0.f);
    *reinterpret_cast<float4*>(&outp[(size_t)node * C + c0]) = o;
    if constexpr (DUAL) {
        ushort4 u;
        __hip_bfloat16 b0 = __float2bfloat16(o.x); u.x = *reinterpret_cast<ushort*>(&b0);
        __hip_bfloat16 b1 = __float2bfloat16(o.y); u.y = *reinterpret_cast<ushort*>(&b1);
        __hip_bfloat16 b2 = __float2bfloat16(o.z); u.z = *reinterpret_cast<ushort*>(&b2);
        __hip_bfloat16 b3 = __float2bfloat16(o.w); u.w = *reinterpret_cast<ushort*>(&b3);
        *reinterpret_cast<ushort4*>(&outb[(size_t)node * C + c0]) = u;
    }
}

// ---------------- GCN head ----------------

__global__ __launch_bounds__(256) void gcn_gemm_kernel(const float* __restrict__ A,
                                                       const float* __restrict__ Wg,
                                                       float* __restrict__ g, int n) {
    __shared__ float W[128 * 8];
    for (int i = threadIdx.x; i < 1024; i += 256) W[i] = Wg[i];
    __syncthreads();
    int gid = blockIdx.x * 256 + threadIdx.x;
    if (gid >= n * 8) return;
    int node = gid >> 3, c = gid & 7;
    const float* ap = A + (size_t)node * 128;
    float acc = 0.f;
    #pragma unroll
    for (int k = 0; k < 128; k += 4) {
        float4 av = *reinterpret_cast<const float4*>(ap + k);
        acc += av.x * W[(k + 0) * 8 + c] + av.y * W[(k + 1) * 8 + c] +
               av.z * W[(k + 2) * 8 + c] + av.w * W[(k + 3) * 8 + c];
    }
    g[gid] = acc;
}

__global__ __launch_bounds__(256) void gcn_agg_kernel(const float* __restrict__ g,
                                                      const float* __restrict__ dinv,
                                                      const int* __restrict__ off,
                                                      const int* __restrict__ ssrc,
                                                      const float* __restrict__ bg,
                                                      float* __restrict__ outp, int n) {
    int gid = blockIdx.x * 256 + threadIdx.x;
    if (gid >= n * 8) return;
    int node = gid >> 3, c = gid & 7;
    int o0 = off[node], o1 = off[node + 1];
    float acc = 0.f;
    for (int i = o0; i < o1; ++i) {
        int s = ssrc[i];
        acc += g[(size_t)s * 8 + c] * dinv[s];
    }
    outp[gid] = acc * dinv[node] + bg[c];
}

// ---------------- launch ----------------

extern "C" void kernel_launch(void* const* d_in, const int* in_sizes, int n_in,
                              void* d_out, int out_size, void* d_ws, size_t ws_size,
                              hipStream_t stream) {
    const float* x      = (const float*)d_in[0];
    const int*   ei     = (const int*)d_in[1];
    const float* W1     = (const float*)d_in[2];
    const float* att_s1 = (const float*)d_in[3];
    const float* att_d1 = (const float*)d_in[4];
    const float* b1     = (const float*)d_in[5];
    const float* W2     = (const float*)d_in[6];
    const float* att_s2 = (const float*)d_in[7];
    const float* att_d2 = (const float*)d_in[8];
    const float* b2     = (const float*)d_in[9];
    const float* Wg     = (const float*)d_in[10];
    const float* bg     = (const float*)d_in[11];
    float* out = (float*)d_out;

    const int n    = in_sizes[0] / 128;  // 50000
    const int E    = in_sizes[1] / 2;    // 500000
    const int Etot = E + n;              // 550000

    // workspace carve-up (~123 MB) with region reuse:
    //   reg3: h1b bf16 [n,256]   -> out2 fp32 [n,128]   (h1b dead after agg1)
    //   reg4: xb  bf16 [n,128]   -> h2b  bf16 [n,128]   (xb dead after gemm1)
    float*  ws     = (float*)d_ws;
    float*  out1   = ws;                               // [n*256] fp32
    float*  reg2   = out1 + (size_t)n * 256;           // [n*128]: out1b bf16 [n,256]
    float*  reg3   = reg2 + (size_t)n * 128;           // [n*128]
    float*  reg4   = reg3 + (size_t)n * 128;           // [n*64]
    float*  a_s    = reg4 + (size_t)n * 64;            // [n*8]
    float*  a_d    = a_s + (size_t)n * 8;              // [n*8]
    float*  g      = a_d + (size_t)n * 8;              // [n*8]
    float*  dinv   = g + (size_t)n * 8;                // [n]
    float*  w1s    = dinv + n;                         // [1024]
    float*  w1d    = w1s + 1024;                       // [1024]
    float*  w2s    = w1d + 1024;                       // [2048]
    float*  w2d    = w2s + 2048;                       // [2048]
    float*  w1t_f  = w2d + 2048;                       // W1t bf16 [256][128]
    float*  w2t_f  = w1t_f + 16384;                    // W2t bf16 [128][256]
    int*    off    = (int*)(w2t_f + 16384);            // [n+1]
    int*    deg    = off + (n + 1);                    // [n]
    int*    cur    = deg + n;                          // [n]
    int*    ssrc   = cur + n;                          // [Etot]
    int*    bsum   = ssrc + Etot;                      // [<=256]

    ushort* out1b = (ushort*)reg2;
    ushort* h1b   = (ushort*)reg3;
    float*  out2  = reg3;
    ushort* xb    = (ushort*)reg4;
    ushort* h2b   = (ushort*)reg4;
    ushort* W1t   = (ushort*)w1t_f;
    ushort* W2t   = (ushort*)w2t_f;

    const dim3 b256(256);
    const int nch = (n + 255) / 256;

    // CSR build
    zero_deg_kernel<<<nch, b256, 0, stream>>>(deg, n);
    hist_kernel<<<(Etot + 255) / 256, b256, 0, stream>>>(ei, E, Etot, deg);
    scanA_kernel<<<nch, b256, 0, stream>>>(deg, off, bsum, n);
    scanB_kernel<<<1, b256, 0, stream>>>(bsum, nch);
    scanC_kernel<<<nch, b256, 0, stream>>>(deg, off, bsum, cur, dinv, n);
    scatter_kernel<<<(Etot + 255) / 256, b256, 0, stream>>>(ei, E, Etot, cur, ssrc);

    // tiny preps: factored attn weights, bf16 input/weight copies
    wprep_kernel<128, 32><<<4, b256, 0, stream>>>(W1, att_s1, att_d1, w1s, w1d);
    wprep_kernel<256, 16><<<8, b256, 0, stream>>>(W2, att_s2, att_d2, w2s, w2d);
    cvt_bf16_kernel<<<(n * 128 / 4 + 255) / 256, b256, 0, stream>>>(x, xb, n * 128);
    wtrans_kernel<128, 256><<<(32768 + 255) / 256, b256, 0, stream>>>(W1, W1t);
    wtrans_kernel<256, 128><<<(32768 + 255) / 256, b256, 0, stream>>>(W2, W2t);

    // layer 1: GAT(128 -> 8x32)
    adots_kernel<128><<<(n * 8 + 255) / 256, b256, 0, stream>>>(x, w1s, w1d, a_s, a_d, n);
    mfma_gemm_kernel<128, 256, 128><<<dim3(2, (n + 127) / 128), b256, 0, stream>>>(xb, W1t, h1b, n);
    gat_agg_kernel<256, 32, true><<<(n + 3) / 4, b256, 0, stream>>>(h1b, a_s, a_d, off, ssrc, b1, out1, out1b, n);

    // layer 2: GAT(256 -> 8x16)
    adots_kernel<256><<<(n * 8 + 255) / 256, b256, 0, stream>>>(out1, w2s, w2d, a_s, a_d, n);
    mfma_gemm_kernel<256, 128, 64><<<dim3(2, (n + 127) / 128), b256, 0, stream>>>(out1b, W2t, h2b, n);
    gat_agg_kernel<128, 16, false><<<(n + 7) / 8, b256, 0, stream>>>(h2b, a_s, a_d, off, ssrc, b2, out2, nullptr, n);

    // GCN head
    gcn_gemm_kernel<<<(n * 8 + 255) / 256, b256, 0, stream>>>(out2, Wg, g, n);
    gcn_agg_kernel<<<(n * 8 + 255) / 256, b256, 0, stream>>>(g, dinv, off, ssrc, bg, out, n);
}

// Round 7
// 263.342 us; speedup vs baseline: 1.6071x; 1.0662x over previous
//
#include <hip/hip_runtime.h>
#include <hip/hip_bf16.h>

// ---------------------------------------------------------------------------
// GATsmall: 2x GATConv (8 heads) + GCNConv head. N=50000, E=500000 (+N self
// loops). Round 7: all inter-layer tensors bf16 (gather tables AND attn/gcn
// inputs); fused agg uses shuffle-shared exp (one lrelu+exp per edge per
// head-GROUP, distributed via __shfl) to cut redundant VALU 8x/4x.
// bf16 MFMA GEMMs (16x16x32, fp32 accum); fp32-factored attention logits.
// ---------------------------------------------------------------------------

typedef __attribute__((ext_vector_type(8))) short bf16x8;
typedef __attribute__((ext_vector_type(4))) float f32x4;

// ---------------- CSR build ----------------

__global__ __launch_bounds__(256) void zero_deg_kernel(int* __restrict__ deg, int n) {
    int i = blockIdx.x * 256 + threadIdx.x;
    if (i < n) deg[i] = 0;
}

__global__ __launch_bounds__(256) void hist_kernel(const int* __restrict__ ei, int E, int Etot,
                                                   int* __restrict__ deg) {
    int e = blockIdx.x * 256 + threadIdx.x;
    if (e >= Etot) return;
    int d = (e < E) ? ei[E + e] : (e - E);  // tail = self loops
    atomicAdd(&deg[d], 1);
}

__global__ __launch_bounds__(256) void scanA_kernel(const int* __restrict__ deg,
                                                    int* __restrict__ off,
                                                    int* __restrict__ bsum, int n) {
    __shared__ int buf[256];
    int t = threadIdx.x;
    int i = blockIdx.x * 256 + t;
    int v = (i < n) ? deg[i] : 0;
    buf[t] = v;
    __syncthreads();
    #pragma unroll
    for (int st = 1; st < 256; st <<= 1) {
        int x = (t >= st) ? buf[t - st] : 0;
        __syncthreads();
        buf[t] += x;
        __syncthreads();
    }
    if (i < n) off[i + 1] = buf[t];
    if (t == 255) bsum[blockIdx.x] = buf[255];
}

__global__ __launch_bounds__(256) void scanB_kernel(int* __restrict__ bsum, int nb) {
    __shared__ int buf[256];
    int t = threadIdx.x;
    int v = (t < nb) ? bsum[t] : 0;
    buf[t] = v;
    __syncthreads();
    #pragma unroll
    for (int st = 1; st < 256; st <<= 1) {
        int x = (t >= st) ? buf[t - st] : 0;
        __syncthreads();
        buf[t] += x;
        __syncthreads();
    }
    if (t < nb) bsum[t] = buf[t] - v;  // exclusive prefix of chunk sums
}

__global__ __launch_bounds__(256) void scanC_kernel(const int* __restrict__ deg,
                                                    int* __restrict__ off,
                                                    const int* __restrict__ bsum,
                                                    int* __restrict__ cur,
                                                    float* __restrict__ dinv, int n) {
    int i = blockIdx.x * 256 + threadIdx.x;
    if (i < n) {
        int o = off[i + 1] + bsum[blockIdx.x];
        off[i + 1] = o;
        cur[i] = o - deg[i];
        dinv[i] = rsqrtf((float)deg[i]);  // deg >= 1 (self loop)
    }
    if (i == 0) off[0] = 0;
}

__global__ __launch_bounds__(256) void scatter_kernel(const int* __restrict__ ei, int E, int Etot,
                                                      int* __restrict__ cur,
                                                      int* __restrict__ ssrc) {
    int e = blockIdx.x * 256 + threadIdx.x;
    if (e >= Etot) return;
    int s, d;
    if (e < E) { s = ei[e]; d = ei[E + e]; }
    else       { s = e - E; d = e - E; }
    int pos = atomicAdd(&cur[d], 1);
    ssrc[pos] = s;
}

// ---------------- helpers ----------------

__device__ __forceinline__ float4 bf4_to_f4(uint2 v) {
    float4 r;
    r.x = __uint_as_float((v.x & 0xFFFFu) << 16);
    r.y = __uint_as_float(v.x & 0xFFFF0000u);
    r.z = __uint_as_float((v.y & 0xFFFFu) << 16);
    r.w = __uint_as_float(v.y & 0xFFFF0000u);
    return r;
}

__global__ __launch_bounds__(256) void cvt_bf16_kernel(const float* __restrict__ in,
                                                       ushort* __restrict__ outb, int count) {
    int i = (blockIdx.x * 256 + threadIdx.x) * 4;
    if (i >= count) return;
    float4 v = *reinterpret_cast<const float4*>(in + i);
    ushort4 u;
    __hip_bfloat16 b0 = __float2bfloat16(v.x); u.x = *reinterpret_cast<ushort*>(&b0);
    __hip_bfloat16 b1 = __float2bfloat16(v.y); u.y = *reinterpret_cast<ushort*>(&b1);
    __hip_bfloat16 b2 = __float2bfloat16(v.z); u.z = *reinterpret_cast<ushort*>(&b2);
    __hip_bfloat16 b3 = __float2bfloat16(v.w); u.w = *reinterpret_cast<ushort*>(&b3);
    *reinterpret_cast<ushort4*>(outb + i) = u;
}

// W [K][NC] fp32 -> Wt [NC][K] bf16
template <int K, int NC>
__global__ __launch_bounds__(256) void wtrans_kernel(const float* __restrict__ W,
                                                     ushort* __restrict__ Wt) {
    int t = blockIdx.x * 256 + threadIdx.x;  // t = nidx*K + k
    if (t >= K * NC) return;
    int nn = t / K, k = t % K;
    __hip_bfloat16 b = __float2bfloat16(W[(size_t)k * NC + nn]);
    Wt[t] = *reinterpret_cast<ushort*>(&b);
}

// ---------------- factored attention weights: w[k][h] = W[k,:] . att[h] -----

template <int K, int D>
__global__ __launch_bounds__(256) void wprep_kernel(const float* __restrict__ W,
                                                    const float* __restrict__ att_s,
                                                    const float* __restrict__ att_d,
                                                    float* __restrict__ ws,
                                                    float* __restrict__ wd) {
    int t = blockIdx.x * 256 + threadIdx.x;  // t = k*8 + h
    if (t >= K * 8) return;
    int k = t >> 3, h = t & 7;
    const float* wrow = W + (size_t)k * (8 * D) + h * D;
    const float* as = att_s + h * D;
    const float* ad = att_d + h * D;
    float s1 = 0.f, s2 = 0.f;
    #pragma unroll
    for (int d = 0; d < D; d += 4) {
        float4 wv = *reinterpret_cast<const float4*>(wrow + d);
        float4 av = *reinterpret_cast<const float4*>(as + d);
        float4 dv = *reinterpret_cast<const float4*>(ad + d);
        s1 += wv.x * av.x + wv.y * av.y + wv.z * av.z + wv.w * av.w;
        s2 += wv.x * dv.x + wv.y * dv.y + wv.z * dv.z + wv.w * dv.w;
    }
    ws[t] = s1;
    wd[t] = s2;
}

// a_s[n][8], a_d[n][8] = Xb[n,K](bf16) @ ws/wd[K,8] (fp32 accumulate)
template <int K>
__global__ __launch_bounds__(256) void adots_kernel(const ushort* __restrict__ Xb,
                                                    const float* __restrict__ ws,
                                                    const float* __restrict__ wd,
                                                    float* __restrict__ a_s,
                                                    float* __restrict__ a_d, int n) {
    int gid = blockIdx.x * 256 + threadIdx.x;
    if (gid >= n * 8) return;
    int node = gid >> 3, h = gid & 7;
    const ushort* xp = Xb + (size_t)node * K;
    float s1 = 0.f, s2 = 0.f;
    #pragma unroll 4
    for (int k = 0; k < K; k += 8) {
        uint4 v = *reinterpret_cast<const uint4*>(xp + k);
        float4 x0 = bf4_to_f4(make_uint2(v.x, v.y));
        float4 x1 = bf4_to_f4(make_uint2(v.z, v.w));
        s1 += x0.x * ws[(k + 0) * 8 + h] + x0.y * ws[(k + 1) * 8 + h] +
              x0.z * ws[(k + 2) * 8 + h] + x0.w * ws[(k + 3) * 8 + h] +
              x1.x * ws[(k + 4) * 8 + h] + x1.y * ws[(k + 5) * 8 + h] +
              x1.z * ws[(k + 6) * 8 + h] + x1.w * ws[(k + 7) * 8 + h];
        s2 += x0.x * wd[(k + 0) * 8 + h] + x0.y * wd[(k + 1) * 8 + h] +
              x0.z * wd[(k + 2) * 8 + h] + x0.w * wd[(k + 3) * 8 + h] +
              x1.x * wd[(k + 4) * 8 + h] + x1.y * wd[(k + 5) * 8 + h] +
              x1.z * wd[(k + 6) * 8 + h] + x1.w * wd[(k + 7) * 8 + h];
    }
    a_s[gid] = s1;
    a_d[gid] = s2;
}

// ---------------- bf16 MFMA GEMM: Cb[M,NC] = Ab[M,K] @ Bt[NC,K]^T -----------

template <int K, int NC, int BN>
__global__ __launch_bounds__(256) void mfma_gemm_kernel(const ushort* __restrict__ Ab,
                                                        const ushort* __restrict__ Bt,
                                                        ushort* __restrict__ Cb, int M) {
    constexpr int BM = 128, BK = 32;
    constexpr int FN = BN / 32;
    __shared__ ushort As[BM * BK];
    __shared__ ushort Bs[BN * BK];
    const int tid = threadIdx.x;
    const int lane = tid & 63;
    const int wid = tid >> 6;
    const int bm = blockIdx.y * BM;
    const int bn = blockIdx.x * BN;
    const int wm = (wid >> 1) * 64;
    const int wn = (wid & 1) * (BN / 2);
    const int l15 = lane & 15;
    const int l4 = lane >> 4;
    f32x4 zero4 = {0.f, 0.f, 0.f, 0.f};
    f32x4 acc[4][FN];
    #pragma unroll
    for (int i = 0; i < 4; ++i)
        #pragma unroll
        for (int j = 0; j < FN; ++j) acc[i][j] = zero4;

    for (int k0 = 0; k0 < K; k0 += BK) {
        #pragma unroll
        for (int p = 0; p < 2; ++p) {
            int ci = tid + p * 256;
            int r = ci >> 2, c = ci & 3;
            int row = bm + r;
            uint4 v = make_uint4(0, 0, 0, 0);
            if (row < M) v = *reinterpret_cast<const uint4*>(&Ab[(size_t)row * K + k0 + c * 8]);
            *reinterpret_cast<uint4*>(&As[r * BK + c * 8]) = v;
        }
        #pragma unroll
        for (int p = 0; p < BN / 64; ++p) {
            int ci = tid + p * 256;
            int r = ci >> 2, c = ci & 3;
            uint4 v = *reinterpret_cast<const uint4*>(&Bt[(size_t)(bn + r) * K + k0 + c * 8]);
            *reinterpret_cast<uint4*>(&Bs[r * BK + c * 8]) = v;
        }
        __syncthreads();
        bf16x8 af[4], bfr[FN];
        #pragma unroll
        for (int i = 0; i < 4; ++i)
            af[i] = *reinterpret_cast<const bf16x8*>(&As[(wm + 16 * i + l15) * BK + l4 * 8]);
        #pragma unroll
        for (int j = 0; j < FN; ++j)
            bfr[j] = *reinterpret_cast<const bf16x8*>(&Bs[(wn + 16 * j + l15) * BK + l4 * 8]);
        #pragma unroll
        for (int i = 0; i < 4; ++i)
            #pragma unroll
            for (int j = 0; j < FN; ++j)
                acc[i][j] = __builtin_amdgcn_mfma_f32_16x16x32_bf16(af[i], bfr[j], acc[i][j], 0, 0, 0);
        __syncthreads();
    }
    #pragma unroll
    for (int i = 0; i < 4; ++i) {
        #pragma unroll
        for (int p = 0; p < 4; ++p) {
            int row = bm + wm + 16 * i + l4 * 4 + p;
            if (row < M) {
                #pragma unroll
                for (int j = 0; j < FN; ++j) {
                    __hip_bfloat16 hb = __float2bfloat16(acc[i][j][p]);
                    Cb[(size_t)row * NC + bn + wn + 16 * j + l15] = *reinterpret_cast<ushort*>(&hb);
                }
            }
        }
    }
}

// ---------------- fused GAT aggregation (softmax + bf16 gather) -------------
// C/4 lanes per node; GS = DH/4 lanes share one head. Lane subl computes
// exp(lrelu(.)) for edge i+subl only; src indices and ev values distributed
// via __shfl width=GS (ds_bpermute: off the VALU pipe). GS gathers in
// flight per lane. Sum(ev*h)/(Sum(ev)+eps) == reference alpha exactly.

#define LRELU_EXP(e) __expf((e) > 0.f ? (e) : 0.2f * (e))

template <int C, int DH>
__global__ __launch_bounds__(256) void gat_agg_kernel(const ushort* __restrict__ hfeat,
                                                      const float* __restrict__ a_src,
                                                      const float* __restrict__ a_dst,
                                                      const int* __restrict__ off,
                                                      const int* __restrict__ ssrc,
                                                      const float* __restrict__ bias,
                                                      ushort* __restrict__ outb, int n) {
    constexpr int LPN = C / 4;   // 64 (layer1) or 32 (layer2) lanes per node
    constexpr int GS = DH / 4;   // 8 (layer1) or 4 (layer2) lanes per head
    const int node = blockIdx.x * (256 / LPN) + threadIdx.x / LPN;
    if (node >= n) return;
    const int local = threadIdx.x & (LPN - 1);
    const int c0 = local * 4;
    const int h = c0 / DH;
    const int subl = local & (GS - 1);
    const float adst = a_dst[node * 8 + h];
    const int o0 = off[node], o1 = off[node + 1];
    float ax = 0.f, ay = 0.f, az = 0.f, aw = 0.f, ssum = 0.f;
    int i = o0;
    const int nfull = o0 + ((o1 - o0) / GS) * GS;
    for (; i < nfull; i += GS) {
        int smy = ssrc[i + subl];
        float e = a_src[smy * 8 + h] + adst;
        float evmy = LRELU_EXP(e);
        int sj[GS];
        #pragma unroll
        for (int j = 0; j < GS; ++j) sj[j] = __shfl(smy, j, GS);
        uint2 rv[GS];
        #pragma unroll
        for (int j = 0; j < GS; ++j)
            rv[j] = *reinterpret_cast<const uint2*>(&hfeat[(size_t)sj[j] * C + c0]);
        #pragma unroll
        for (int j = 0; j < GS; ++j) {
            float ev = __shfl(evmy, j, GS);
            float4 hv = bf4_to_f4(rv[j]);
            ssum += ev;
            ax += ev * hv.x; ay += ev * hv.y; az += ev * hv.z; aw += ev * hv.w;
        }
    }
    for (; i < o1; ++i) {
        int s = ssrc[i];
        float e = a_src[s * 8 + h] + adst;
        float v = LRELU_EXP(e);
        uint2 rvv = *reinterpret_cast<const uint2*>(&hfeat[(size_t)s * C + c0]);
        float4 hv = bf4_to_f4(rvv);
        ssum += v;
        ax += v * hv.x; ay += v * hv.y; az += v * hv.z; aw += v * hv.w;
    }
    float sinv = 1.f / (ssum + 1e-16f);
    float4 bb = *reinterpret_cast<const float4*>(bias + c0);
    float ox = fmaxf(ax * sinv + bb.x, 0.f);
    float oy = fmaxf(ay * sinv + bb.y, 0.f);
    float oz = fmaxf(az * sinv + bb.z, 0.f);
    float ow = fmaxf(aw * sinv + bb.w, 0.f);
    ushort4 u;
    __hip_bfloat16 b0 = __float2bfloat16(ox); u.x = *reinterpret_cast<ushort*>(&b0);
    __hip_bfloat16 b1 = __float2bfloat16(oy); u.y = *reinterpret_cast<ushort*>(&b1);
    __hip_bfloat16 b2 = __float2bfloat16(oz); u.z = *reinterpret_cast<ushort*>(&b2);
    __hip_bfloat16 b3 = __float2bfloat16(ow); u.w = *reinterpret_cast<ushort*>(&b3);
    *reinterpret_cast<ushort4*>(&outb[(size_t)node * C + c0]) = u;
}

// ---------------- GCN head ----------------

__global__ __launch_bounds__(256) void gcn_gemm_kernel(const ushort* __restrict__ Ab,
                                                       const float* __restrict__ Wg,
                                                       float* __restrict__ g, int n) {
    __shared__ float W[128 * 8];
    for (int i = threadIdx.x; i < 1024; i += 256) W[i] = Wg[i];
    __syncthreads();
    int gid = blockIdx.x * 256 + threadIdx.x;
    if (gid >= n * 8) return;
    int node = gid >> 3, c = gid & 7;
    const ushort* ap = Ab + (size_t)node * 128;
    float acc = 0.f;
    #pragma unroll
    for (int k = 0; k < 128; k += 8) {
        uint4 v = *reinterpret_cast<const uint4*>(ap + k);
        float4 x0 = bf4_to_f4(make_uint2(v.x, v.y));
        float4 x1 = bf4_to_f4(make_uint2(v.z, v.w));
        acc += x0.x * W[(k + 0) * 8 + c] + x0.y * W[(k + 1) * 8 + c] +
               x0.z * W[(k + 2) * 8 + c] + x0.w * W[(k + 3) * 8 + c] +
               x1.x * W[(k + 4) * 8 + c] + x1.y * W[(k + 5) * 8 + c] +
               x1.z * W[(k + 6) * 8 + c] + x1.w * W[(k + 7) * 8 + c];
    }
    g[gid] = acc;
}

__global__ __launch_bounds__(256) void gcn_agg_kernel(const float* __restrict__ g,
                                                      const float* __restrict__ dinv,
                                                      const int* __restrict__ off,
                                                      const int* __restrict__ ssrc,
                                                      const float* __restrict__ bg,
                                                      float* __restrict__ outp, int n) {
    int gid = blockIdx.x * 256 + threadIdx.x;
    if (gid >= n * 8) return;
    int node = gid >> 3, c = gid & 7;
    int o0 = off[node], o1 = off[node + 1];
    float acc = 0.f;
    for (int i = o0; i < o1; ++i) {
        int s = ssrc[i];
        acc += g[(size_t)s * 8 + c] * dinv[s];
    }
    outp[gid] = acc * dinv[node] + bg[c];
}

// ---------------- launch ----------------

extern "C" void kernel_launch(void* const* d_in, const int* in_sizes, int n_in,
                              void* d_out, int out_size, void* d_ws, size_t ws_size,
                              hipStream_t stream) {
    const float* x      = (const float*)d_in[0];
    const int*   ei     = (const int*)d_in[1];
    const float* W1     = (const float*)d_in[2];
    const float* att_s1 = (const float*)d_in[3];
    const float* att_d1 = (const float*)d_in[4];
    const float* b1     = (const float*)d_in[5];
    const float* W2     = (const float*)d_in[6];
    const float* att_s2 = (const float*)d_in[7];
    const float* att_d2 = (const float*)d_in[8];
    const float* b2     = (const float*)d_in[9];
    const float* Wg     = (const float*)d_in[10];
    const float* bg     = (const float*)d_in[11];
    float* out = (float*)d_out;

    const int n    = in_sizes[0] / 128;  // 50000
    const int E    = in_sizes[1] / 2;    // 500000
    const int Etot = E + n;              // 550000

    // workspace carve-up (~70 MB), with region reuse:
    //   regA: h1b bf16 [n,256]  -> out2b bf16 [n,128] (h1b dead after agg1)
    //   regC: xb  bf16 [n,128]  -> h2b  bf16 [n,128]  (xb dead after gemm1)
    float*  wsp   = (float*)d_ws;
    float*  regA  = wsp;                              // [n*128] floats
    float*  regB  = regA + (size_t)n * 128;           // [n*128]: out1b bf16 [n,256]
    float*  regC  = regB + (size_t)n * 128;           // [n*64]
    float*  a_s   = regC + (size_t)n * 64;            // [n*8]
    float*  a_d   = a_s + (size_t)n * 8;              // [n*8]
    float*  g     = a_d + (size_t)n * 8;              // [n*8]
    float*  dinv  = g + (size_t)n * 8;                // [n]
    float*  w1s   = dinv + n;                         // [1024]
    float*  w1d   = w1s + 1024;                       // [1024]
    float*  w2s   = w1d + 1024;                       // [2048]
    float*  w2d   = w2s + 2048;                       // [2048]
    float*  w1t_f = w2d + 2048;                       // W1t bf16 [256][128]
    float*  w2t_f = w1t_f + 16384;                    // W2t bf16 [128][256]
    int*    off   = (int*)(w2t_f + 16384);            // [n+1]
    int*    deg   = off + (n + 1);                    // [n]
    int*    cur   = deg + n;                          // [n]
    int*    ssrc  = cur + n;                          // [Etot]
    int*    bsum  = ssrc + Etot;                      // [<=256]

    ushort* h1b   = (ushort*)regA;
    ushort* out2b = (ushort*)regA;
    ushort* out1b = (ushort*)regB;
    ushort* xb    = (ushort*)regC;
    ushort* h2b   = (ushort*)regC;
    ushort* W1t   = (ushort*)w1t_f;
    ushort* W2t   = (ushort*)w2t_f;

    const dim3 b256(256);
    const int nch = (n + 255) / 256;

    // CSR build
    zero_deg_kernel<<<nch, b256, 0, stream>>>(deg, n);
    hist_kernel<<<(Etot + 255) / 256, b256, 0, stream>>>(ei, E, Etot, deg);
    scanA_kernel<<<nch, b256, 0, stream>>>(deg, off, bsum, n);
    scanB_kernel<<<1, b256, 0, stream>>>(bsum, nch);
    scanC_kernel<<<nch, b256, 0, stream>>>(deg, off, bsum, cur, dinv, n);
    scatter_kernel<<<(Etot + 255) / 256, b256, 0, stream>>>(ei, E, Etot, cur, ssrc);

    // tiny preps: factored attn weights, bf16 input/weight copies
    wprep_kernel<128, 32><<<4, b256, 0, stream>>>(W1, att_s1, att_d1, w1s, w1d);
    wprep_kernel<256, 16><<<8, b256, 0, stream>>>(W2, att_s2, att_d2, w2s, w2d);
    cvt_bf16_kernel<<<(n * 128 / 4 + 255) / 256, b256, 0, stream>>>(x, xb, n * 128);
    wtrans_kernel<128, 256><<<(32768 + 255) / 256, b256, 0, stream>>>(W1, W1t);
    wtrans_kernel<256, 128><<<(32768 + 255) / 256, b256, 0, stream>>>(W2, W2t);

    // layer 1: GAT(128 -> 8x32)
    adots_kernel<128><<<(n * 8 + 255) / 256, b256, 0, stream>>>(xb, w1s, w1d, a_s, a_d, n);
    mfma_gemm_kernel<128, 256, 128><<<dim3(2, (n + 127) / 128), b256, 0, stream>>>(xb, W1t, h1b, n);
    gat_agg_kernel<256, 32><<<(n + 3) / 4, b256, 0, stream>>>(h1b, a_s, a_d, off, ssrc, b1, out1b, n);

    // layer 2: GAT(256 -> 8x16)
    adots_kernel<256><<<(n * 8 + 255) / 256, b256, 0, stream>>>(out1b, w2s, w2d, a_s, a_d, n);
    mfma_gemm_kernel<256, 128, 64><<<dim3(2, (n + 127) / 128), b256, 0, stream>>>(out1b, W2t, h2b, n);
    gat_agg_kernel<128, 16><<<(n + 7) / 8, b256, 0, stream>>>(h2b, a_s, a_d, off, ssrc, b2, out2b, n);

    // GCN head
    gcn_gemm_kernel<<<(n * 8 + 255) / 256, b256, 0, stream>>>(out2b, Wg, g, n);
    gcn_agg_kernel<<<(n * 8 + 255) / 256, b256, 0, stream>>>(g, dinv, off, ssrc, bg, out, n);
}